// Round 12
// baseline (579.815 us; speedup 1.0000x reference)
//
#include <hip/hip_runtime.h>
#include <float.h>

#define BQ 8
#define CHN 96
#define NP 3136
#define KNN 9
#define C2 192
#define NT 196        // 16-wide tiles along n/m
#define MCH 4         // m-chunks
#define TPC (NT/MCH)  // 49 tiles per chunk
#define NFRAG 9       // 3-way split: h0,h1,h2,m0,m1,m2,l0,l1,l2
#define NLIST 16      // partial top-9 lists per query (4 m-chunks x 4 lane-groups)

typedef __attribute__((ext_vector_type(8))) short bf16x8;
typedef __attribute__((ext_vector_type(4))) float f32x4;

__device__ inline ushort f2bf(float x) {            // round-to-nearest-even
  unsigned u = __float_as_uint(x);
  return (ushort)((u + 0x7FFFu + ((u >> 16) & 1u)) >> 16);
}
__device__ inline float bf2f(ushort h) { return __uint_as_float((unsigned)h << 16); }

// ---------- K1: h[b][o][n] = sum_c fc1_w[o][c] * x[b][c][n] + fc1_b[o]
__global__ __launch_bounds__(256) void k1_conv1(const float* __restrict__ x,
    const float* __restrict__ w, const float* __restrict__ bias, float* __restrict__ h) {
  __shared__ float sw[CHN * CHN];
  __shared__ float sx[CHN][64];
  int b = blockIdx.y;
  int n0 = blockIdx.x * 64;
  int tid = threadIdx.x;
  for (int i = tid; i < CHN * CHN; i += 256) sw[i] = w[i];
  const float* xb = x + (size_t)b * CHN * NP + n0;
  for (int i = tid; i < CHN * 64; i += 256) {
    int c = i >> 6, nn = i & 63;
    sx[c][nn] = xb[(size_t)c * NP + nn];
  }
  __syncthreads();
  int nn = tid & 63;
  int o0 = (tid >> 6) * 24;
  float acc[24];
#pragma unroll
  for (int j = 0; j < 24; ++j) acc[j] = 0.f;
  for (int c = 0; c < CHN; ++c) {
    float xv = sx[c][nn];
#pragma unroll
    for (int j = 0; j < 24; ++j) acc[j] = fmaf(sw[(o0 + j) * CHN + c], xv, acc[j]);
  }
  float* hb = h + (size_t)b * CHN * NP + n0;
#pragma unroll
  for (int j = 0; j < 24; ++j) hb[(size_t)(o0 + j) * NP + nn] = acc[j] + bias[o0 + j];
}

// ---------- K2/K7: per-(b,channel) mean + rstd
__global__ __launch_bounds__(256) void k2_stats(const float* __restrict__ src,
                                                float* __restrict__ stat) {
  int bo = blockIdx.x;
  const float* p = src + (size_t)bo * NP;
  float s = 0.f, ss = 0.f;
  for (int i = threadIdx.x; i < NP; i += 256) { float v = p[i]; s += v; ss = fmaf(v, v, ss); }
#pragma unroll
  for (int off = 32; off; off >>= 1) { s += __shfl_down(s, off); ss += __shfl_down(ss, off); }
  __shared__ float as[4], ass[4];
  int wv = threadIdx.x >> 6;
  if ((threadIdx.x & 63) == 0) { as[wv] = s; ass[wv] = ss; }
  __syncthreads();
  if (threadIdx.x == 0) {
    float S = as[0] + as[1] + as[2] + as[3];
    float SS = ass[0] + ass[1] + ass[2] + ass[3];
    float mean = S * (1.f / NP);
    float var = SS * (1.f / NP) - mean * mean;
    if (var < 0.f) var = 0.f;
    stat[bo * 2] = mean;
    stat[bo * 2 + 1] = 1.f / sqrtf(var + 1e-5f);
  }
}

// ---------- K3: normalize h -> feats[b][n][c]; nrm = feats/max(||f||,eps); sq = sum(nrm^2)
__global__ __launch_bounds__(256) void k3_norm(const float* __restrict__ h,
    const float* __restrict__ stat, float* __restrict__ feats, float* __restrict__ nrm,
    float* __restrict__ sq) {
  __shared__ float tile[CHN][33];
  __shared__ float part[8][32];
  __shared__ float sinv[32];
  int b = blockIdx.y, n0 = blockIdx.x * 32;
  int tid = threadIdx.x;
  for (int i = tid; i < CHN * 32; i += 256) {
    int c = i >> 5, nn = i & 31;
    float m = stat[(b * CHN + c) * 2];
    float r = stat[(b * CHN + c) * 2 + 1];
    tile[c][nn] = (h[((size_t)(b * CHN + c)) * NP + n0 + nn] - m) * r;
  }
  __syncthreads();
  int nn = tid & 31, sub = tid >> 5;
  float ss = 0.f;
#pragma unroll
  for (int j = 0; j < 12; ++j) { float f = tile[sub * 12 + j][nn]; ss = fmaf(f, f, ss); }
  part[sub][nn] = ss;
  __syncthreads();
  if (tid < 32) {
    float S = 0.f;
#pragma unroll
    for (int w = 0; w < 8; ++w) S += part[w][tid];
    float norm = sqrtf(S);
    sinv[tid] = 1.f / fmaxf(norm, 1e-12f);
  }
  __syncthreads();
  float inv = sinv[nn];
  float ss2 = 0.f;
#pragma unroll
  for (int j = 0; j < 12; ++j) { float f = tile[sub * 12 + j][nn] * inv; ss2 = fmaf(f, f, ss2); }
  part[sub][nn] = ss2;
  __syncthreads();
  if (tid < 32) {
    float S = 0.f;
#pragma unroll
    for (int w = 0; w < 8; ++w) S += part[w][tid];
    sq[(size_t)b * NP + n0 + tid] = S;
  }
  for (int i = tid; i < 32 * CHN; i += 256) {
    int nn2 = i / CHN, c = i - nn2 * CHN;
    float f = tile[c][nn2];
    size_t o = ((size_t)b * NP + n0 + nn2) * CHN + c;
    feats[o] = f;
    nrm[o] = f * sinv[nn2];
  }
}

// ---------- K3b: build MFMA operand streams, 3-way bf16 split
__global__ __launch_bounds__(256) void k3b_prep(const float* __restrict__ nrm,
    ushort* __restrict__ ast, ushort* __restrict__ bst) {
  int b = blockIdx.y, t = blockIdx.x;
  int tid = threadIdx.x;
  const float* nb = nrm + (size_t)b * NP * CHN;
  ushort* ao = ast + (((size_t)b * NT + t) * NFRAG) * 512;
  for (int e = tid; e < NFRAG * 512; e += 256) {
    int f = e >> 9, l = (e >> 3) & 63, j = e & 7;
    int part = f / 3, sl = f - part * 3;
    int c = sl * 32 + (l >> 4) * 8 + j;
    int m = t * 16 + (l & 15);
    float xv = nb[(size_t)m * CHN + c];
    ushort hh = f2bf(xv);
    float rm = xv - bf2f(hh);          // exact
    ushort md = f2bf(rm);
    ushort v = (part == 0) ? hh : (part == 1) ? md : f2bf(rm - bf2f(md));
    ao[e] = v;
  }
  ushort* bo = bst + (((size_t)b * NT + t) * NFRAG) * 512;
  for (int e = tid; e < NFRAG * 512; e += 256) {
    int f = e >> 9, l = (e >> 3) & 63, j = e & 7;
    int part = f / 3, sl = f - part * 3;
    int c = sl * 32 + (l >> 4) * 8 + j;
    int n = t * 16 + (l & 15);
    float y = -2.f * nb[(size_t)n * CHN + c];
    ushort hh = f2bf(y);
    float rm = y - bf2f(hh);
    ushort md = f2bf(rm);
    ushort v = (part == 0) ? hh : (part == 1) ? md : f2bf(rm - bf2f(md));
    bo[e] = v;
  }
}

// ---------- K4 v7.1: identical math/structure to round-11's 186us version;
// split along chunk into TWO dispatches (chunk = blockIdx.y + chunk0) so
// rocprof's top-5 (which only shows the slowest kernel) exposes the next
// hotspot. Writes disjoint; per-block work unchanged.
#define CSWAP(vI, iI, vJ, iJ) do { \
    bool _s = (vJ) < (vI); \
    float _fa = _s ? (vJ) : (vI); float _fb = _s ? (vI) : (vJ); \
    int _ia = _s ? (iJ) : (iI); int _ib = _s ? (iI) : (iJ); \
    (vI) = _fa; (vJ) = _fb; (iI) = _ia; (iJ) = _ib; \
  } while (0)

__global__ __launch_bounds__(256) void k4_mfma(
    const ushort* __restrict__ ast, const ushort* __restrict__ bst,
    const float* __restrict__ sq, float* __restrict__ pd, int* __restrict__ pi,
    int chunk0) {
  int b = blockIdx.z, chunk = blockIdx.y + chunk0, ng = blockIdx.x;
  int wave = threadIdx.x >> 6, lane = threadIdx.x & 63;
  int tn = ng * 4 + wave;

  // B tile -> wave-private LDS (once). No __syncthreads needed anywhere:
  // each wave reads only its own region; in-wave ds ordering via lgkmcnt.
  __shared__ ushort lds_b[4 * NFRAG * 512];   // 36,864 B
  {
    const bf16x8* bp = (const bf16x8*)(bst + (((size_t)b * NT + tn) * NFRAG) * 512);
    bf16x8* dst = (bf16x8*)(lds_b + wave * (NFRAG * 512));
#pragma unroll
    for (int f = 0; f < NFRAG; ++f) dst[f * 64 + lane] = bp[f * 64 + lane];
  }
  const bf16x8* bl = (const bf16x8*)(lds_b + wave * (NFRAG * 512));

  const float* sqb = sq + (size_t)b * NP;
  const ushort* astb = ast + ((size_t)b * NT) * (NFRAG * 512);
  int t0 = chunk * TPC;
  const size_t TS = (size_t)NFRAG * 512;

  float tv0 = FLT_MAX, tv1 = FLT_MAX, tv2 = FLT_MAX, tv3 = FLT_MAX, tv4 = FLT_MAX;
  float tv5 = FLT_MAX, tv6 = FLT_MAX, tv7 = FLT_MAX, tv8 = FLT_MAX;
  int ti0 = 0x7fffffff, ti1 = 0x7fffffff, ti2 = 0x7fffffff, ti3 = 0x7fffffff;
  int ti4 = 0x7fffffff, ti5 = 0x7fffffff, ti6 = 0x7fffffff, ti7 = 0x7fffffff;
  int ti8 = 0x7fffffff;

  for (int tl = 0; tl < TPC; ++tl) {
    const bf16x8* ap = (const bf16x8*)(astb + (size_t)(t0 + tl) * TS);
    // all 9 A fragments up front — compiler batches loads, sinks waits
    bf16x8 aH0 = ap[0 * 64 + lane], aH1 = ap[1 * 64 + lane], aH2 = ap[2 * 64 + lane];
    bf16x8 aM0 = ap[3 * 64 + lane], aM1 = ap[4 * 64 + lane], aM2 = ap[5 * 64 + lane];
    bf16x8 aL0 = ap[6 * 64 + lane], aL1 = ap[7 * 64 + lane], aL2 = ap[8 * 64 + lane];
    int mbase = (t0 + tl) * 16 + ((lane >> 4) << 2);
    float4 sqv = *(const float4*)(sqb + mbase);
    f32x4 acc0 = {0.f, 0.f, 0.f, 0.f}, acc1 = {0.f, 0.f, 0.f, 0.f};
    f32x4 acc2 = {0.f, 0.f, 0.f, 0.f}, acc3 = {0.f, 0.f, 0.f, 0.f};
#pragma unroll
    for (int s = 0; s < 3; ++s) {
      bf16x8 aH = (s == 0) ? aH0 : (s == 1) ? aH1 : aH2;
      bf16x8 aM = (s == 0) ? aM0 : (s == 1) ? aM1 : aM2;
      bf16x8 aL = (s == 0) ? aL0 : (s == 1) ? aL1 : aL2;
      bf16x8 bH = bl[(0 + s) * 64 + lane];   // just-in-time B reads: 8 live regs
      bf16x8 bM = bl[(3 + s) * 64 + lane];
      bf16x8 bL = bl[(6 + s) * 64 + lane];
      acc0 = __builtin_amdgcn_mfma_f32_16x16x32_bf16(aH, bH, acc0, 0, 0, 0);
      acc1 = __builtin_amdgcn_mfma_f32_16x16x32_bf16(aM, bH, acc1, 0, 0, 0);
      acc2 = __builtin_amdgcn_mfma_f32_16x16x32_bf16(aL, bH, acc2, 0, 0, 0);
      acc3 = __builtin_amdgcn_mfma_f32_16x16x32_bf16(aH, bM, acc3, 0, 0, 0);
      acc2 = __builtin_amdgcn_mfma_f32_16x16x32_bf16(aH, bL, acc2, 0, 0, 0);
      acc3 = __builtin_amdgcn_mfma_f32_16x16x32_bf16(aM, bM, acc3, 0, 0, 0);
    }
#pragma unroll
    for (int r = 0; r < 4; ++r) {   // small terms first, then hh, then exact sq_m
      float d = (((acc1[r] + acc3[r]) + acc2[r]) + acc0[r]) + sqv[r];
      int m = mbase + r;
      if (d < tv8) {                // strict <: equal keys keep earlier index
        tv8 = d; ti8 = m;
        CSWAP(tv7, ti7, tv8, ti8);
        CSWAP(tv6, ti6, tv7, ti7);
        CSWAP(tv5, ti5, tv6, ti6);
        CSWAP(tv4, ti4, tv5, ti5);
        CSWAP(tv3, ti3, tv4, ti4);
        CSWAP(tv2, ti2, tv3, ti3);
        CSWAP(tv1, ti1, tv2, ti2);
        CSWAP(tv0, ti0, tv1, ti1);
      }
    }
  }
  int g = lane >> 4;
  int n = tn * 16 + (lane & 15);
  size_t base = (((size_t)b * NLIST + (chunk * 4 + g)) * NP + n) * (size_t)KNN;
  pd[base + 0] = tv0; pi[base + 0] = ti0;
  pd[base + 1] = tv1; pi[base + 1] = ti1;
  pd[base + 2] = tv2; pi[base + 2] = ti2;
  pd[base + 3] = tv3; pi[base + 3] = ti3;
  pd[base + 4] = tv4; pi[base + 4] = ti4;
  pd[base + 5] = tv5; pi[base + 5] = ti5;
  pd[base + 6] = tv6; pi[base + 6] = ti6;
  pd[base + 7] = tv7; pi[base + 7] = ti7;
  pd[base + 8] = tv8; pi[base + 8] = ti8;
}

// ---------- K4b: merge 16 sorted top-9 lists per query
__global__ __launch_bounds__(64) void k4b_merge(const float* __restrict__ pd,
    const int* __restrict__ pi, int* __restrict__ nidx) {
  __shared__ float  sd[64][NLIST * KNN + 1];
  __shared__ ushort si[64][NLIST * KNN + 1];
  int tid = threadIdx.x;
  int q = blockIdx.x * 64 + tid;
  int b = q / NP, n = q - b * NP;
  for (int ch = 0; ch < NLIST; ++ch) {
    size_t base = (((size_t)b * NLIST + ch) * NP + n) * (size_t)KNN;
#pragma unroll
    for (int k = 0; k < KNN; ++k) {
      sd[tid][ch * KNN + k] = pd[base + k];
      si[tid][ch * KNN + k] = (ushort)pi[base + k];
    }
  }
  float dl = -FLT_MAX; int il = -1;
  int* op = nidx + (size_t)q * KNN;
  for (int k = 0; k < KNN; ++k) {
    float bd = FLT_MAX; int bi = 0x7fffffff;
    for (int j = 0; j < NLIST * KNN; ++j) {
      float d = sd[tid][j]; int i = (int)si[tid][j];
      bool gt = (d > dl) || ((d == dl) && (i > il));
      bool lt = (d < bd) || ((d == bd) && (i < bi));
      if (gt && lt) { bd = d; bi = i; }
    }
    op[k] = bi; dl = bd; il = bi;
  }
}

// ---------- K5: a = (W1-W2)·f + gb ; u = W2·f
__global__ __launch_bounds__(256) void k5_au(const float* __restrict__ feats,
    const float* __restrict__ gw, const float* __restrict__ gb,
    float* __restrict__ a, float* __restrict__ u) {
  __shared__ float sf[32][97];
  __shared__ float swc[64 * C2];
  int b = blockIdx.y, n0 = blockIdx.x * 32;
  int tid = threadIdx.x;
  for (int i = tid; i < 32 * CHN; i += 256) {
    int nn = i / CHN, c = i - nn * CHN;
    sf[nn][c] = feats[((size_t)b * NP + n0 + nn) * CHN + c];
  }
  int nn = tid & 31, sub = tid >> 5;
  for (int oc = 0; oc < 3; ++oc) {
    __syncthreads();
    for (int i = tid; i < 64 * C2; i += 256) swc[i] = gw[(size_t)(oc * 64) * C2 + i];
    __syncthreads();
    float accA[8], accU[8];
#pragma unroll
    for (int j = 0; j < 8; ++j) { accA[j] = 0.f; accU[j] = 0.f; }
    for (int c = 0; c < CHN; ++c) {
      float f = sf[nn][c];
#pragma unroll
      for (int j = 0; j < 8; ++j) {
        float w1 = swc[(sub * 8 + j) * C2 + c];
        float wv2 = swc[(sub * 8 + j) * C2 + 96 + c];
        accA[j] = fmaf(w1 - wv2, f, accA[j]);
        accU[j] = fmaf(wv2, f, accU[j]);
      }
    }
    size_t row = ((size_t)b * NP + n0 + nn) * C2;
#pragma unroll
    for (int j = 0; j < 8; ++j) {
      int o = oc * 64 + sub * 8 + j;
      a[row + o] = accA[j] + gb[o];
      u[row + o] = accU[j];
    }
  }
}

// ---------- K6: agg = relu(a + max_k u[idx_k]); ol = fc2_w·agg + fc2_b
__global__ __launch_bounds__(256) void k6_edge(const float* __restrict__ a,
    const float* __restrict__ u, const int* __restrict__ nidx,
    const float* __restrict__ w2, const float* __restrict__ b2, float* __restrict__ ol) {
  __shared__ float sagg[32][193];
  int b = blockIdx.y, n0 = blockIdx.x * 32;
  int tid = threadIdx.x;
  int wv = tid >> 6, ln = tid & 63;
  for (int p = 0; p < 8; ++p) {
    int nn = wv * 8 + p;
    size_t row = (size_t)b * NP + n0 + nn;
    const int* ip = nidx + row * KNN;
    int idx[KNN];
#pragma unroll
    for (int k = 0; k < KNN; ++k) idx[k] = ip[k];
#pragma unroll
    for (int oo = 0; oo < 3; ++oo) {
      int o = oo * 64 + ln;
      float umax = -FLT_MAX;
#pragma unroll
      for (int k = 0; k < KNN; ++k)
        umax = fmaxf(umax, u[((size_t)b * NP + idx[k]) * C2 + o]);
      float av = a[row * C2 + o];
      sagg[nn][o] = fmaxf(av + umax, 0.f);
    }
  }
  __syncthreads();
  int nn = tid & 31, sub = tid >> 5;
  for (int j = 0; j < 12; ++j) {
    int o2 = sub + 8 * j;
    float acc = b2[o2];
    for (int o = 0; o < C2; ++o) acc = fmaf(w2[o2 * C2 + o], sagg[nn][o], acc);
    ol[((size_t)b * CHN + o2) * NP + n0 + nn] = acc;
  }
}

// ---------- K8: out = (ol - mean)*rstd + shortcut
__global__ __launch_bounds__(256) void k8_final(const float* __restrict__ ol,
    const float* __restrict__ stat, const float* __restrict__ x, float* __restrict__ out) {
  int i = blockIdx.x * 256 + threadIdx.x;
  int bo = i / NP;
  float m = stat[bo * 2], r = stat[bo * 2 + 1];
  out[i] = fmaf(ol[i] - m, r, x[i]);
}

extern "C" void kernel_launch(void* const* d_in, const int* in_sizes, int n_in,
                              void* d_out, int out_size, void* d_ws, size_t ws_size,
                              hipStream_t stream) {
  const float* x   = (const float*)d_in[0];
  const float* f1w = (const float*)d_in[1];
  const float* f1b = (const float*)d_in[2];
  const float* gw  = (const float*)d_in[3];
  const float* gb  = (const float*)d_in[4];
  const float* f2w = (const float*)d_in[5];
  const float* f2b = (const float*)d_in[6];
  float* out = (float*)d_out;
  char* ws = (char*)d_ws;

  constexpr size_t SZ_MAT = (size_t)BQ * CHN * NP * 4;           // 9,633,792
  constexpr size_t SZ_STR = (size_t)BQ * NT * NFRAG * 512 * 2;   // 14,450,688
  constexpr size_t SZ_PL  = (size_t)BQ * NLIST * NP * KNN * 4;   // 14,450,688
  constexpr size_t OFF_H   = 0;
  constexpr size_t OFF_PD  = 0;
  constexpr size_t OFF_PI  = OFF_PD + SZ_PL;
  constexpr size_t OFF_A   = 0;
  constexpr size_t OFF_AST = 2 * SZ_PL;
  constexpr size_t OFF_BST = OFF_AST + SZ_STR;
  constexpr size_t OFF_U   = OFF_AST;
  constexpr size_t OFF_NRM = OFF_AST + 2 * SZ_STR;
  constexpr size_t OFF_OL  = OFF_NRM;
  constexpr size_t OFF_FE  = OFF_NRM + SZ_MAT;
  constexpr size_t OFF_SQ  = OFF_FE + SZ_MAT;
  constexpr size_t OFF_ST1 = OFF_SQ + (size_t)BQ * NP * 4;
  constexpr size_t OFF_ST2 = OFF_ST1 + (size_t)BQ * CHN * 2 * 4;
  constexpr size_t OFF_NI  = OFF_ST2 + (size_t)BQ * CHN * 2 * 4;

  float* h   = (float*)(ws + OFF_H);
  float* fe  = (float*)(ws + OFF_FE);
  float* nrm = (float*)(ws + OFF_NRM);
  float* sq  = (float*)(ws + OFF_SQ);
  float* st1 = (float*)(ws + OFF_ST1);
  float* st2 = (float*)(ws + OFF_ST2);
  int*   ni  = (int*)(ws + OFF_NI);
  ushort* ast = (ushort*)(ws + OFF_AST);
  ushort* bst = (ushort*)(ws + OFF_BST);
  float* pd  = (float*)(ws + OFF_PD);
  int*   pi  = (int*)(ws + OFF_PI);
  float* aA  = (float*)(ws + OFF_A);
  float* uU  = (float*)(ws + OFF_U);
  float* ol  = (float*)(ws + OFF_OL);

  k1_conv1<<<dim3(NP / 64, BQ), 256, 0, stream>>>(x, f1w, f1b, h);
  k2_stats<<<dim3(BQ * CHN), 256, 0, stream>>>(h, st1);
  k3_norm<<<dim3(NP / 32, BQ), 256, 0, stream>>>(h, st1, fe, nrm, sq);
  k3b_prep<<<dim3(NT, BQ), 256, 0, stream>>>(nrm, ast, bst);
  // k4 split into two chunk-pair dispatches (measurement: drops k4 instances
  // to ~95us so rocprof top-5 reveals the next-slowest kernels)
  k4_mfma<<<dim3(NT / 4, 2, BQ), 256, 0, stream>>>(ast, bst, sq, pd, pi, 0);
  k4_mfma<<<dim3(NT / 4, 2, BQ), 256, 0, stream>>>(ast, bst, sq, pd, pi, 2);
  k4b_merge<<<dim3(BQ * NP / 64), 64, 0, stream>>>(pd, pi, ni);
  k5_au<<<dim3(NP / 32, BQ), 256, 0, stream>>>(fe, gw, gb, aA, uU);
  k6_edge<<<dim3(NP / 32, BQ), 256, 0, stream>>>(aA, uU, ni, f2w, f2b, ol);
  k2_stats<<<dim3(BQ * CHN), 256, 0, stream>>>(ol, st2);
  k8_final<<<dim3(BQ * CHN * NP / 256), 256, 0, stream>>>(ol, st2, x, out);
}

// Round 13
// 437.482 us; speedup vs baseline: 1.3253x; 1.3253x over previous
//
#include <hip/hip_runtime.h>
#include <float.h>

#define BQ 8
#define CHN 96
#define NP 3136
#define KNN 9
#define C2 192
#define NT 196        // 16-wide tiles along n/m
#define MCH 4         // m-chunks
#define TPC (NT/MCH)  // 49 tiles per chunk
#define NFRAG 9       // 3-way split: h0,h1,h2,m0,m1,m2,l0,l1,l2
#define NLIST 16      // partial top-9 lists per query (4 m-chunks x 4 lane-groups)

typedef __attribute__((ext_vector_type(8))) short bf16x8;
typedef __attribute__((ext_vector_type(4))) float f32x4;

__device__ inline ushort f2bf(float x) {            // round-to-nearest-even
  unsigned u = __float_as_uint(x);
  return (ushort)((u + 0x7FFFu + ((u >> 16) & 1u)) >> 16);
}
__device__ inline float bf2f(ushort h) { return __uint_as_float((unsigned)h << 16); }

// ---------- K1: h[b][o][n] = sum_c fc1_w[o][c] * x[b][c][n] + fc1_b[o]
__global__ __launch_bounds__(256) void k1_conv1(const float* __restrict__ x,
    const float* __restrict__ w, const float* __restrict__ bias, float* __restrict__ h) {
  __shared__ float sw[CHN * CHN];
  __shared__ float sx[CHN][64];
  int b = blockIdx.y;
  int n0 = blockIdx.x * 64;
  int tid = threadIdx.x;
  for (int i = tid; i < CHN * CHN; i += 256) sw[i] = w[i];
  const float* xb = x + (size_t)b * CHN * NP + n0;
  for (int i = tid; i < CHN * 64; i += 256) {
    int c = i >> 6, nn = i & 63;
    sx[c][nn] = xb[(size_t)c * NP + nn];
  }
  __syncthreads();
  int nn = tid & 63;
  int o0 = (tid >> 6) * 24;
  float acc[24];
#pragma unroll
  for (int j = 0; j < 24; ++j) acc[j] = 0.f;
  for (int c = 0; c < CHN; ++c) {
    float xv = sx[c][nn];
#pragma unroll
    for (int j = 0; j < 24; ++j) acc[j] = fmaf(sw[(o0 + j) * CHN + c], xv, acc[j]);
  }
  float* hb = h + (size_t)b * CHN * NP + n0;
#pragma unroll
  for (int j = 0; j < 24; ++j) hb[(size_t)(o0 + j) * NP + nn] = acc[j] + bias[o0 + j];
}

// ---------- K2/K7: per-(b,channel) mean + rstd
__global__ __launch_bounds__(256) void k2_stats(const float* __restrict__ src,
                                                float* __restrict__ stat) {
  int bo = blockIdx.x;
  const float* p = src + (size_t)bo * NP;
  float s = 0.f, ss = 0.f;
  for (int i = threadIdx.x; i < NP; i += 256) { float v = p[i]; s += v; ss = fmaf(v, v, ss); }
#pragma unroll
  for (int off = 32; off; off >>= 1) { s += __shfl_down(s, off); ss += __shfl_down(ss, off); }
  __shared__ float as[4], ass[4];
  int wv = threadIdx.x >> 6;
  if ((threadIdx.x & 63) == 0) { as[wv] = s; ass[wv] = ss; }
  __syncthreads();
  if (threadIdx.x == 0) {
    float S = as[0] + as[1] + as[2] + as[3];
    float SS = ass[0] + ass[1] + ass[2] + ass[3];
    float mean = S * (1.f / NP);
    float var = SS * (1.f / NP) - mean * mean;
    if (var < 0.f) var = 0.f;
    stat[bo * 2] = mean;
    stat[bo * 2 + 1] = 1.f / sqrtf(var + 1e-5f);
  }
}

// ---------- K3: normalize h -> feats[b][n][c]; nrm = feats/max(||f||,eps); sq = sum(nrm^2)
__global__ __launch_bounds__(256) void k3_norm(const float* __restrict__ h,
    const float* __restrict__ stat, float* __restrict__ feats, float* __restrict__ nrm,
    float* __restrict__ sq) {
  __shared__ float tile[CHN][33];
  __shared__ float part[8][32];
  __shared__ float sinv[32];
  int b = blockIdx.y, n0 = blockIdx.x * 32;
  int tid = threadIdx.x;
  for (int i = tid; i < CHN * 32; i += 256) {
    int c = i >> 5, nn = i & 31;
    float m = stat[(b * CHN + c) * 2];
    float r = stat[(b * CHN + c) * 2 + 1];
    tile[c][nn] = (h[((size_t)(b * CHN + c)) * NP + n0 + nn] - m) * r;
  }
  __syncthreads();
  int nn = tid & 31, sub = tid >> 5;
  float ss = 0.f;
#pragma unroll
  for (int j = 0; j < 12; ++j) { float f = tile[sub * 12 + j][nn]; ss = fmaf(f, f, ss); }
  part[sub][nn] = ss;
  __syncthreads();
  if (tid < 32) {
    float S = 0.f;
#pragma unroll
    for (int w = 0; w < 8; ++w) S += part[w][tid];
    float norm = sqrtf(S);
    sinv[tid] = 1.f / fmaxf(norm, 1e-12f);
  }
  __syncthreads();
  float inv = sinv[nn];
  float ss2 = 0.f;
#pragma unroll
  for (int j = 0; j < 12; ++j) { float f = tile[sub * 12 + j][nn] * inv; ss2 = fmaf(f, f, ss2); }
  part[sub][nn] = ss2;
  __syncthreads();
  if (tid < 32) {
    float S = 0.f;
#pragma unroll
    for (int w = 0; w < 8; ++w) S += part[w][tid];
    sq[(size_t)b * NP + n0 + tid] = S;
  }
  for (int i = tid; i < 32 * CHN; i += 256) {
    int nn2 = i / CHN, c = i - nn2 * CHN;
    float f = tile[c][nn2];
    size_t o = ((size_t)b * NP + n0 + nn2) * CHN + c;
    feats[o] = f;
    nrm[o] = f * sinv[nn2];
  }
}

// ---------- K3b: build MFMA operand streams, 3-way bf16 split
__global__ __launch_bounds__(256) void k3b_prep(const float* __restrict__ nrm,
    ushort* __restrict__ ast, ushort* __restrict__ bst) {
  int b = blockIdx.y, t = blockIdx.x;
  int tid = threadIdx.x;
  const float* nb = nrm + (size_t)b * NP * CHN;
  ushort* ao = ast + (((size_t)b * NT + t) * NFRAG) * 512;
  for (int e = tid; e < NFRAG * 512; e += 256) {
    int f = e >> 9, l = (e >> 3) & 63, j = e & 7;
    int part = f / 3, sl = f - part * 3;
    int c = sl * 32 + (l >> 4) * 8 + j;
    int m = t * 16 + (l & 15);
    float xv = nb[(size_t)m * CHN + c];
    ushort hh = f2bf(xv);
    float rm = xv - bf2f(hh);          // exact
    ushort md = f2bf(rm);
    ushort v = (part == 0) ? hh : (part == 1) ? md : f2bf(rm - bf2f(md));
    ao[e] = v;
  }
  ushort* bo = bst + (((size_t)b * NT + t) * NFRAG) * 512;
  for (int e = tid; e < NFRAG * 512; e += 256) {
    int f = e >> 9, l = (e >> 3) & 63, j = e & 7;
    int part = f / 3, sl = f - part * 3;
    int c = sl * 32 + (l >> 4) * 8 + j;
    int n = t * 16 + (l & 15);
    float y = -2.f * nb[(size_t)n * CHN + c];
    ushort hh = f2bf(y);
    float rm = y - bf2f(hh);
    ushort md = f2bf(rm);
    ushort v = (part == 0) ? hh : (part == 1) ? md : f2bf(rm - bf2f(md));
    bo[e] = v;
  }
}

// ---------- K4 v7 (round-11 proven, 186us): wave-private-LDS B, named tv/ti,
// single dispatch (round-12 split tax was ~36us; measurement done).
#define CSWAP(vI, iI, vJ, iJ) do { \
    bool _s = (vJ) < (vI); \
    float _fa = _s ? (vJ) : (vI); float _fb = _s ? (vI) : (vJ); \
    int _ia = _s ? (iJ) : (iI); int _ib = _s ? (iI) : (iJ); \
    (vI) = _fa; (vJ) = _fb; (iI) = _ia; (iJ) = _ib; \
  } while (0)

__global__ __launch_bounds__(256) void k4_mfma(
    const ushort* __restrict__ ast, const ushort* __restrict__ bst,
    const float* __restrict__ sq, float* __restrict__ pd, int* __restrict__ pi,
    int chunk0) {
  int b = blockIdx.z, chunk = blockIdx.y + chunk0, ng = blockIdx.x;
  int wave = threadIdx.x >> 6, lane = threadIdx.x & 63;
  int tn = ng * 4 + wave;

  __shared__ ushort lds_b[4 * NFRAG * 512];   // 36,864 B, wave-private regions
  {
    const bf16x8* bp = (const bf16x8*)(bst + (((size_t)b * NT + tn) * NFRAG) * 512);
    bf16x8* dst = (bf16x8*)(lds_b + wave * (NFRAG * 512));
#pragma unroll
    for (int f = 0; f < NFRAG; ++f) dst[f * 64 + lane] = bp[f * 64 + lane];
  }
  const bf16x8* bl = (const bf16x8*)(lds_b + wave * (NFRAG * 512));

  const float* sqb = sq + (size_t)b * NP;
  const ushort* astb = ast + ((size_t)b * NT) * (NFRAG * 512);
  int t0 = chunk * TPC;
  const size_t TS = (size_t)NFRAG * 512;

  float tv0 = FLT_MAX, tv1 = FLT_MAX, tv2 = FLT_MAX, tv3 = FLT_MAX, tv4 = FLT_MAX;
  float tv5 = FLT_MAX, tv6 = FLT_MAX, tv7 = FLT_MAX, tv8 = FLT_MAX;
  int ti0 = 0x7fffffff, ti1 = 0x7fffffff, ti2 = 0x7fffffff, ti3 = 0x7fffffff;
  int ti4 = 0x7fffffff, ti5 = 0x7fffffff, ti6 = 0x7fffffff, ti7 = 0x7fffffff;
  int ti8 = 0x7fffffff;

  for (int tl = 0; tl < TPC; ++tl) {
    const bf16x8* ap = (const bf16x8*)(astb + (size_t)(t0 + tl) * TS);
    bf16x8 aH0 = ap[0 * 64 + lane], aH1 = ap[1 * 64 + lane], aH2 = ap[2 * 64 + lane];
    bf16x8 aM0 = ap[3 * 64 + lane], aM1 = ap[4 * 64 + lane], aM2 = ap[5 * 64 + lane];
    bf16x8 aL0 = ap[6 * 64 + lane], aL1 = ap[7 * 64 + lane], aL2 = ap[8 * 64 + lane];
    int mbase = (t0 + tl) * 16 + ((lane >> 4) << 2);
    float4 sqv = *(const float4*)(sqb + mbase);
    f32x4 acc0 = {0.f, 0.f, 0.f, 0.f}, acc1 = {0.f, 0.f, 0.f, 0.f};
    f32x4 acc2 = {0.f, 0.f, 0.f, 0.f}, acc3 = {0.f, 0.f, 0.f, 0.f};
#pragma unroll
    for (int s = 0; s < 3; ++s) {
      bf16x8 aH = (s == 0) ? aH0 : (s == 1) ? aH1 : aH2;
      bf16x8 aM = (s == 0) ? aM0 : (s == 1) ? aM1 : aM2;
      bf16x8 aL = (s == 0) ? aL0 : (s == 1) ? aL1 : aL2;
      bf16x8 bH = bl[(0 + s) * 64 + lane];
      bf16x8 bM = bl[(3 + s) * 64 + lane];
      bf16x8 bL = bl[(6 + s) * 64 + lane];
      acc0 = __builtin_amdgcn_mfma_f32_16x16x32_bf16(aH, bH, acc0, 0, 0, 0);
      acc1 = __builtin_amdgcn_mfma_f32_16x16x32_bf16(aM, bH, acc1, 0, 0, 0);
      acc2 = __builtin_amdgcn_mfma_f32_16x16x32_bf16(aL, bH, acc2, 0, 0, 0);
      acc3 = __builtin_amdgcn_mfma_f32_16x16x32_bf16(aH, bM, acc3, 0, 0, 0);
      acc2 = __builtin_amdgcn_mfma_f32_16x16x32_bf16(aH, bL, acc2, 0, 0, 0);
      acc3 = __builtin_amdgcn_mfma_f32_16x16x32_bf16(aM, bM, acc3, 0, 0, 0);
    }
#pragma unroll
    for (int r = 0; r < 4; ++r) {
      float d = (((acc1[r] + acc3[r]) + acc2[r]) + acc0[r]) + sqv[r];
      int m = mbase + r;
      if (d < tv8) {                // strict <: equal keys keep earlier index
        tv8 = d; ti8 = m;
        CSWAP(tv7, ti7, tv8, ti8);
        CSWAP(tv6, ti6, tv7, ti7);
        CSWAP(tv5, ti5, tv6, ti6);
        CSWAP(tv4, ti4, tv5, ti5);
        CSWAP(tv3, ti3, tv4, ti4);
        CSWAP(tv2, ti2, tv3, ti3);
        CSWAP(tv1, ti1, tv2, ti2);
        CSWAP(tv0, ti0, tv1, ti1);
      }
    }
  }
  int g = lane >> 4;
  int n = tn * 16 + (lane & 15);
  size_t base = (((size_t)b * NLIST + (chunk * 4 + g)) * NP + n) * (size_t)KNN;
  pd[base + 0] = tv0; pi[base + 0] = ti0;
  pd[base + 1] = tv1; pi[base + 1] = ti1;
  pd[base + 2] = tv2; pi[base + 2] = ti2;
  pd[base + 3] = tv3; pi[base + 3] = ti3;
  pd[base + 4] = tv4; pi[base + 4] = ti4;
  pd[base + 5] = tv5; pi[base + 5] = ti5;
  pd[base + 6] = tv6; pi[base + 6] = ti6;
  pd[base + 7] = tv7; pi[base + 7] = ti7;
  pd[base + 8] = tv8; pi[base + 8] = ti8;
}

// ---------- K4b v2: two-phase 4-wide k-way merge of 16 SORTED top-9 lists.
// Round-12 profile: old selection scan was 124us — 1 thread/query (392 waves
// total, 4.3% occupancy) x 1296 serial comparisons. v2: 4 threads/query
// (1568 waves); phase 1 = each thread 4-way-merges 4 lists by head-pick
// (9 steps, reads only consumed entries); phase 2 = s==0 thread merges the
// 4 survivor lists from LDS. Lexicographic (d, idx) order preserved exactly.
#define ARGMIN4(e0, j0, e1, j1, e2, j2, e3, j3, DW, IW, W0, W1, W2, W3) \
  bool _l01 = ((e0) < (e1)) || ((e0) == (e1) && (j0) < (j1)); \
  float _da = _l01 ? (e0) : (e1); int _ia = _l01 ? (j0) : (j1); \
  bool _l23 = ((e2) < (e3)) || ((e2) == (e3) && (j2) < (j3)); \
  float _db = _l23 ? (e2) : (e3); int _ib = _l23 ? (j2) : (j3); \
  bool _lab = (_da < _db) || (_da == _db && _ia < _ib); \
  float DW = _lab ? _da : _db; int IW = _lab ? _ia : _ib; \
  bool W0 = _lab && _l01, W1 = _lab && !_l01, W2 = !_lab && _l23, W3 = !_lab && !_l23;

__global__ __launch_bounds__(256) void k4b_merge(const float* __restrict__ pd,
    const int* __restrict__ pi, int* __restrict__ nidx) {
  __shared__ float ld_d[256][KNN];   // 9216 B
  __shared__ int   ld_i[256][KNN];   // 9216 B
  int tid = threadIdx.x;
  int gid = blockIdx.x * 256 + tid;
  int q = gid >> 2, s = gid & 3;     // 4 threads per query; group never straddles a wave
  int b = q / NP, n = q - b * NP;
  size_t b0 = (((size_t)b * NLIST + (s * 4 + 0)) * NP + n) * (size_t)KNN;
  size_t b1 = (((size_t)b * NLIST + (s * 4 + 1)) * NP + n) * (size_t)KNN;
  size_t b2 = (((size_t)b * NLIST + (s * 4 + 2)) * NP + n) * (size_t)KNN;
  size_t b3 = (((size_t)b * NLIST + (s * 4 + 3)) * NP + n) * (size_t)KNN;
  int p0 = 0, p1 = 0, p2 = 0, p3 = 0;
  float d0 = pd[b0], d1 = pd[b1], d2 = pd[b2], d3 = pd[b3];
  int i0 = pi[b0], i1 = pi[b1], i2 = pi[b2], i3 = pi[b3];
#pragma unroll
  for (int k = 0; k < KNN; ++k) {
    ARGMIN4(d0, i0, d1, i1, d2, i2, d3, i3, dw, iw, w0, w1, w2, w3);
    ld_d[tid][k] = dw; ld_i[tid][k] = iw;
    if (w0) { ++p0; bool ok = p0 < KNN; d0 = ok ? pd[b0 + p0] : FLT_MAX; i0 = ok ? pi[b0 + p0] : 0x7fffffff; }
    if (w1) { ++p1; bool ok = p1 < KNN; d1 = ok ? pd[b1 + p1] : FLT_MAX; i1 = ok ? pi[b1 + p1] : 0x7fffffff; }
    if (w2) { ++p2; bool ok = p2 < KNN; d2 = ok ? pd[b2 + p2] : FLT_MAX; i2 = ok ? pi[b2 + p2] : 0x7fffffff; }
    if (w3) { ++p3; bool ok = p3 < KNN; d3 = ok ? pd[b3 + p3] : FLT_MAX; i3 = ok ? pi[b3 + p3] : 0x7fffffff; }
  }
  __syncthreads();
  if (s == 0) {
    int h0 = 0, h1 = 0, h2 = 0, h3 = 0;
    float e0 = ld_d[tid][0], e1 = ld_d[tid + 1][0], e2 = ld_d[tid + 2][0], e3 = ld_d[tid + 3][0];
    int j0 = ld_i[tid][0], j1 = ld_i[tid + 1][0], j2 = ld_i[tid + 2][0], j3 = ld_i[tid + 3][0];
    int* op = nidx + (size_t)q * KNN;
#pragma unroll
    for (int k = 0; k < KNN; ++k) {
      ARGMIN4(e0, j0, e1, j1, e2, j2, e3, j3, dw, iw, w0, w1, w2, w3);
      op[k] = iw;
      if (w0) { ++h0; bool ok = h0 < KNN; e0 = ok ? ld_d[tid][h0] : FLT_MAX; j0 = ok ? ld_i[tid][h0] : 0x7fffffff; }
      if (w1) { ++h1; bool ok = h1 < KNN; e1 = ok ? ld_d[tid + 1][h1] : FLT_MAX; j1 = ok ? ld_i[tid + 1][h1] : 0x7fffffff; }
      if (w2) { ++h2; bool ok = h2 < KNN; e2 = ok ? ld_d[tid + 2][h2] : FLT_MAX; j2 = ok ? ld_i[tid + 2][h2] : 0x7fffffff; }
      if (w3) { ++h3; bool ok = h3 < KNN; e3 = ok ? ld_d[tid + 3][h3] : FLT_MAX; j3 = ok ? ld_i[tid + 3][h3] : 0x7fffffff; }
    }
  }
}

// ---------- K5: a = (W1-W2)·f + gb ; u = W2·f
__global__ __launch_bounds__(256) void k5_au(const float* __restrict__ feats,
    const float* __restrict__ gw, const float* __restrict__ gb,
    float* __restrict__ a, float* __restrict__ u) {
  __shared__ float sf[32][97];
  __shared__ float swc[64 * C2];
  int b = blockIdx.y, n0 = blockIdx.x * 32;
  int tid = threadIdx.x;
  for (int i = tid; i < 32 * CHN; i += 256) {
    int nn = i / CHN, c = i - nn * CHN;
    sf[nn][c] = feats[((size_t)b * NP + n0 + nn) * CHN + c];
  }
  int nn = tid & 31, sub = tid >> 5;
  for (int oc = 0; oc < 3; ++oc) {
    __syncthreads();
    for (int i = tid; i < 64 * C2; i += 256) swc[i] = gw[(size_t)(oc * 64) * C2 + i];
    __syncthreads();
    float accA[8], accU[8];
#pragma unroll
    for (int j = 0; j < 8; ++j) { accA[j] = 0.f; accU[j] = 0.f; }
    for (int c = 0; c < CHN; ++c) {
      float f = sf[nn][c];
#pragma unroll
      for (int j = 0; j < 8; ++j) {
        float w1 = swc[(sub * 8 + j) * C2 + c];
        float wv2 = swc[(sub * 8 + j) * C2 + 96 + c];
        accA[j] = fmaf(w1 - wv2, f, accA[j]);
        accU[j] = fmaf(wv2, f, accU[j]);
      }
    }
    size_t row = ((size_t)b * NP + n0 + nn) * C2;
#pragma unroll
    for (int j = 0; j < 8; ++j) {
      int o = oc * 64 + sub * 8 + j;
      a[row + o] = accA[j] + gb[o];
      u[row + o] = accU[j];
    }
  }
}

// ---------- K6: agg = relu(a + max_k u[idx_k]); ol = fc2_w·agg + fc2_b
__global__ __launch_bounds__(256) void k6_edge(const float* __restrict__ a,
    const float* __restrict__ u, const int* __restrict__ nidx,
    const float* __restrict__ w2, const float* __restrict__ b2, float* __restrict__ ol) {
  __shared__ float sagg[32][193];
  int b = blockIdx.y, n0 = blockIdx.x * 32;
  int tid = threadIdx.x;
  int wv = tid >> 6, ln = tid & 63;
  for (int p = 0; p < 8; ++p) {
    int nn = wv * 8 + p;
    size_t row = (size_t)b * NP + n0 + nn;
    const int* ip = nidx + row * KNN;
    int idx[KNN];
#pragma unroll
    for (int k = 0; k < KNN; ++k) idx[k] = ip[k];
#pragma unroll
    for (int oo = 0; oo < 3; ++oo) {
      int o = oo * 64 + ln;
      float umax = -FLT_MAX;
#pragma unroll
      for (int k = 0; k < KNN; ++k)
        umax = fmaxf(umax, u[((size_t)b * NP + idx[k]) * C2 + o]);
      float av = a[row * C2 + o];
      sagg[nn][o] = fmaxf(av + umax, 0.f);
    }
  }
  __syncthreads();
  int nn = tid & 31, sub = tid >> 5;
  for (int j = 0; j < 12; ++j) {
    int o2 = sub + 8 * j;
    float acc = b2[o2];
    for (int o = 0; o < C2; ++o) acc = fmaf(w2[o2 * C2 + o], sagg[nn][o], acc);
    ol[((size_t)b * CHN + o2) * NP + n0 + nn] = acc;
  }
}

// ---------- K8: out = (ol - mean)*rstd + shortcut
__global__ __launch_bounds__(256) void k8_final(const float* __restrict__ ol,
    const float* __restrict__ stat, const float* __restrict__ x, float* __restrict__ out) {
  int i = blockIdx.x * 256 + threadIdx.x;
  int bo = i / NP;
  float m = stat[bo * 2], r = stat[bo * 2 + 1];
  out[i] = fmaf(ol[i] - m, r, x[i]);
}

extern "C" void kernel_launch(void* const* d_in, const int* in_sizes, int n_in,
                              void* d_out, int out_size, void* d_ws, size_t ws_size,
                              hipStream_t stream) {
  const float* x   = (const float*)d_in[0];
  const float* f1w = (const float*)d_in[1];
  const float* f1b = (const float*)d_in[2];
  const float* gw  = (const float*)d_in[3];
  const float* gb  = (const float*)d_in[4];
  const float* f2w = (const float*)d_in[5];
  const float* f2b = (const float*)d_in[6];
  float* out = (float*)d_out;
  char* ws = (char*)d_ws;

  constexpr size_t SZ_MAT = (size_t)BQ * CHN * NP * 4;           // 9,633,792
  constexpr size_t SZ_STR = (size_t)BQ * NT * NFRAG * 512 * 2;   // 14,450,688
  constexpr size_t SZ_PL  = (size_t)BQ * NLIST * NP * KNN * 4;   // 14,450,688
  constexpr size_t OFF_H   = 0;
  constexpr size_t OFF_PD  = 0;
  constexpr size_t OFF_PI  = OFF_PD + SZ_PL;
  constexpr size_t OFF_A   = 0;
  constexpr size_t OFF_AST = 2 * SZ_PL;
  constexpr size_t OFF_BST = OFF_AST + SZ_STR;
  constexpr size_t OFF_U   = OFF_AST;
  constexpr size_t OFF_NRM = OFF_AST + 2 * SZ_STR;
  constexpr size_t OFF_OL  = OFF_NRM;
  constexpr size_t OFF_FE  = OFF_NRM + SZ_MAT;
  constexpr size_t OFF_SQ  = OFF_FE + SZ_MAT;
  constexpr size_t OFF_ST1 = OFF_SQ + (size_t)BQ * NP * 4;
  constexpr size_t OFF_ST2 = OFF_ST1 + (size_t)BQ * CHN * 2 * 4;
  constexpr size_t OFF_NI  = OFF_ST2 + (size_t)BQ * CHN * 2 * 4;

  float* h   = (float*)(ws + OFF_H);
  float* fe  = (float*)(ws + OFF_FE);
  float* nrm = (float*)(ws + OFF_NRM);
  float* sq  = (float*)(ws + OFF_SQ);
  float* st1 = (float*)(ws + OFF_ST1);
  float* st2 = (float*)(ws + OFF_ST2);
  int*   ni  = (int*)(ws + OFF_NI);
  ushort* ast = (ushort*)(ws + OFF_AST);
  ushort* bst = (ushort*)(ws + OFF_BST);
  float* pd  = (float*)(ws + OFF_PD);
  int*   pi  = (int*)(ws + OFF_PI);
  float* aA  = (float*)(ws + OFF_A);
  float* uU  = (float*)(ws + OFF_U);
  float* ol  = (float*)(ws + OFF_OL);

  k1_conv1<<<dim3(NP / 64, BQ), 256, 0, stream>>>(x, f1w, f1b, h);
  k2_stats<<<dim3(BQ * CHN), 256, 0, stream>>>(h, st1);
  k3_norm<<<dim3(NP / 32, BQ), 256, 0, stream>>>(h, st1, fe, nrm, sq);
  k3b_prep<<<dim3(NT, BQ), 256, 0, stream>>>(nrm, ast, bst);
  k4_mfma<<<dim3(NT / 4, MCH, BQ), 256, 0, stream>>>(ast, bst, sq, pd, pi, 0);
  k4b_merge<<<dim3(BQ * NP * 4 / 256), 256, 0, stream>>>(pd, pi, ni);
  k5_au<<<dim3(NP / 32, BQ), 256, 0, stream>>>(fe, gw, gb, aA, uU);
  k6_edge<<<dim3(NP / 32, BQ), 256, 0, stream>>>(aA, uU, ni, f2w, f2b, ol);
  k2_stats<<<dim3(BQ * CHN), 256, 0, stream>>>(ol, st2);
  k8_final<<<dim3(BQ * CHN * NP / 256), 256, 0, stream>>>(ol, st2, x, out);
}

// Round 15
// 414.243 us; speedup vs baseline: 1.3997x; 1.0561x over previous
//
#include <hip/hip_runtime.h>
#include <float.h>

#define BQ 8
#define CHN 96
#define NP 3136
#define KNN 9
#define C2 192
#define NT 196        // 16-wide tiles along n/m
#define MCH 4         // m-chunks
#define TPC (NT/MCH)  // 49 tiles per chunk
#define NFRAG 9       // 3-way split: h0,h1,h2,m0,m1,m2,l0,l1,l2
#define NLIST 16      // partial top-9 lists per query (4 m-chunks x 4 lane-groups)

typedef __attribute__((ext_vector_type(8))) short bf16x8;
typedef __attribute__((ext_vector_type(4))) float f32x4;
typedef __attribute__((ext_vector_type(4))) unsigned int u32x4;

__device__ inline ushort f2bf(float x) {            // round-to-nearest-even
  unsigned u = __float_as_uint(x);
  return (ushort)((u + 0x7FFFu + ((u >> 16) & 1u)) >> 16);
}
__device__ inline float bf2f(ushort h) { return __uint_as_float((unsigned)h << 16); }

// ---------- K1: h[b][o][n] = sum_c fc1_w[o][c] * x[b][c][n] + fc1_b[o]
__global__ __launch_bounds__(256) void k1_conv1(const float* __restrict__ x,
    const float* __restrict__ w, const float* __restrict__ bias, float* __restrict__ h) {
  __shared__ float sw[CHN * CHN];
  __shared__ float sx[CHN][64];
  int b = blockIdx.y;
  int n0 = blockIdx.x * 64;
  int tid = threadIdx.x;
  for (int i = tid; i < CHN * CHN; i += 256) sw[i] = w[i];
  const float* xb = x + (size_t)b * CHN * NP + n0;
  for (int i = tid; i < CHN * 64; i += 256) {
    int c = i >> 6, nn = i & 63;
    sx[c][nn] = xb[(size_t)c * NP + nn];
  }
  __syncthreads();
  int nn = tid & 63;
  int o0 = (tid >> 6) * 24;
  float acc[24];
#pragma unroll
  for (int j = 0; j < 24; ++j) acc[j] = 0.f;
  for (int c = 0; c < CHN; ++c) {
    float xv = sx[c][nn];
#pragma unroll
    for (int j = 0; j < 24; ++j) acc[j] = fmaf(sw[(o0 + j) * CHN + c], xv, acc[j]);
  }
  float* hb = h + (size_t)b * CHN * NP + n0;
#pragma unroll
  for (int j = 0; j < 24; ++j) hb[(size_t)(o0 + j) * NP + nn] = acc[j] + bias[o0 + j];
}

// ---------- K2/K7: per-(b,channel) mean + rstd
__global__ __launch_bounds__(256) void k2_stats(const float* __restrict__ src,
                                                float* __restrict__ stat) {
  int bo = blockIdx.x;
  const float* p = src + (size_t)bo * NP;
  float s = 0.f, ss = 0.f;
  for (int i = threadIdx.x; i < NP; i += 256) { float v = p[i]; s += v; ss = fmaf(v, v, ss); }
#pragma unroll
  for (int off = 32; off; off >>= 1) { s += __shfl_down(s, off); ss += __shfl_down(ss, off); }
  __shared__ float as[4], ass[4];
  int wv = threadIdx.x >> 6;
  if ((threadIdx.x & 63) == 0) { as[wv] = s; ass[wv] = ss; }
  __syncthreads();
  if (threadIdx.x == 0) {
    float S = as[0] + as[1] + as[2] + as[3];
    float SS = ass[0] + ass[1] + ass[2] + ass[3];
    float mean = S * (1.f / NP);
    float var = SS * (1.f / NP) - mean * mean;
    if (var < 0.f) var = 0.f;
    stat[bo * 2] = mean;
    stat[bo * 2 + 1] = 1.f / sqrtf(var + 1e-5f);
  }
}

// ---------- K3: normalize h -> feats[b][n][c]; nrm = feats/max(||f||,eps); sq = sum(nrm^2)
__global__ __launch_bounds__(256) void k3_norm(const float* __restrict__ h,
    const float* __restrict__ stat, float* __restrict__ feats, float* __restrict__ nrm,
    float* __restrict__ sq) {
  __shared__ float tile[CHN][33];
  __shared__ float part[8][32];
  __shared__ float sinv[32];
  int b = blockIdx.y, n0 = blockIdx.x * 32;
  int tid = threadIdx.x;
  for (int i = tid; i < CHN * 32; i += 256) {
    int c = i >> 5, nn = i & 31;
    float m = stat[(b * CHN + c) * 2];
    float r = stat[(b * CHN + c) * 2 + 1];
    tile[c][nn] = (h[((size_t)(b * CHN + c)) * NP + n0 + nn] - m) * r;
  }
  __syncthreads();
  int nn = tid & 31, sub = tid >> 5;
  float ss = 0.f;
#pragma unroll
  for (int j = 0; j < 12; ++j) { float f = tile[sub * 12 + j][nn]; ss = fmaf(f, f, ss); }
  part[sub][nn] = ss;
  __syncthreads();
  if (tid < 32) {
    float S = 0.f;
#pragma unroll
    for (int w = 0; w < 8; ++w) S += part[w][tid];
    float norm = sqrtf(S);
    sinv[tid] = 1.f / fmaxf(norm, 1e-12f);
  }
  __syncthreads();
  float inv = sinv[nn];
  float ss2 = 0.f;
#pragma unroll
  for (int j = 0; j < 12; ++j) { float f = tile[sub * 12 + j][nn] * inv; ss2 = fmaf(f, f, ss2); }
  part[sub][nn] = ss2;
  __syncthreads();
  if (tid < 32) {
    float S = 0.f;
#pragma unroll
    for (int w = 0; w < 8; ++w) S += part[w][tid];
    sq[(size_t)b * NP + n0 + tid] = S;
  }
  for (int i = tid; i < 32 * CHN; i += 256) {
    int nn2 = i / CHN, c = i - nn2 * CHN;
    float f = tile[c][nn2];
    size_t o = ((size_t)b * NP + n0 + nn2) * CHN + c;
    feats[o] = f;
    nrm[o] = f * sinv[nn2];
  }
}

// ---------- K3b: build MFMA A-operand stream only (3-way bf16 split).
// B-side (-2x) derived in-register inside k4: bf16split(-2x) == -2*bf16split(x)
// EXACTLY (x-2 scaling is an exponent shift; split residuals exact by Sterbenz).
__global__ __launch_bounds__(256) void k3b_prep(const float* __restrict__ nrm,
    ushort* __restrict__ ast) {
  int b = blockIdx.y, t = blockIdx.x;
  int tid = threadIdx.x;
  const float* nb = nrm + (size_t)b * NP * CHN;
  ushort* ao = ast + (((size_t)b * NT + t) * NFRAG) * 512;
  for (int e = tid; e < NFRAG * 512; e += 256) {
    int f = e >> 9, l = (e >> 3) & 63, j = e & 7;
    int part = f / 3, sl = f - part * 3;
    int c = sl * 32 + (l >> 4) * 8 + j;
    int m = t * 16 + (l & 15);
    float xv = nb[(size_t)m * CHN + c];
    ushort hh = f2bf(xv);
    float rm = xv - bf2f(hh);          // exact
    ushort md = f2bf(rm);
    ushort v = (part == 0) ? hh : (part == 1) ? md : f2bf(rm - bf2f(md));
    ao[e] = v;
  }
}

// ---------- K4 v8 (round-14 ws-overflow fixed): round-11/13 structure +
//  (a) XCD-pinning swizzle (id%8 const within (b,chunk) stream group)
//  (b) B derived in-register from A stream: exact -2x via (w^0x80008000)+0x00800080
//  (c) s_setprio(1) around MFMA cluster
#define CSWAP(vI, iI, vJ, iJ) do { \
    bool _s = (vJ) < (vI); \
    float _fa = _s ? (vJ) : (vI); float _fb = _s ? (vI) : (vJ); \
    int _ia = _s ? (iJ) : (iI); int _ib = _s ? (iI) : (iJ); \
    (vI) = _fa; (vJ) = _fb; (iI) = _ia; (iJ) = _ib; \
  } while (0)

__device__ inline bf16x8 neg2x(bf16x8 v) {          // exact -2*x on 8 packed bf16
  u32x4 w = __builtin_bit_cast(u32x4, v);
#pragma unroll
  for (int i = 0; i < 4; ++i) w[i] = (w[i] ^ 0x80008000u) + 0x00800080u;
  return __builtin_bit_cast(bf16x8, w);
}

__global__ __launch_bounds__(256) void k4_mfma(
    const ushort* __restrict__ ast, const float* __restrict__ sq,
    float* __restrict__ pd, int* __restrict__ pi) {
  int id = blockIdx.x;
  int g8 = id & 7, r = id >> 3;
  int ng = r % 49, gd = r / 49;          // gd in 0..3
  int group = gd * 8 + g8;               // 0..31, bijective
  int chunk = group & 3, b = group >> 2;
  int wave = threadIdx.x >> 6, lane = threadIdx.x & 63;
  int tn = ng * 4 + wave;

  __shared__ ushort lds_b[4 * NFRAG * 512];   // 36,864 B, wave-private regions
  {
    const bf16x8* bp = (const bf16x8*)(ast + (((size_t)b * NT + tn) * NFRAG) * 512);
    bf16x8* dst = (bf16x8*)(lds_b + wave * (NFRAG * 512));
#pragma unroll
    for (int f = 0; f < NFRAG; ++f) dst[f * 64 + lane] = neg2x(bp[f * 64 + lane]);
  }
  const bf16x8* bl = (const bf16x8*)(lds_b + wave * (NFRAG * 512));

  const float* sqb = sq + (size_t)b * NP;
  const ushort* astb = ast + ((size_t)b * NT) * (NFRAG * 512);
  int t0 = chunk * TPC;
  const size_t TS = (size_t)NFRAG * 512;

  float tv0 = FLT_MAX, tv1 = FLT_MAX, tv2 = FLT_MAX, tv3 = FLT_MAX, tv4 = FLT_MAX;
  float tv5 = FLT_MAX, tv6 = FLT_MAX, tv7 = FLT_MAX, tv8 = FLT_MAX;
  int ti0 = 0x7fffffff, ti1 = 0x7fffffff, ti2 = 0x7fffffff, ti3 = 0x7fffffff;
  int ti4 = 0x7fffffff, ti5 = 0x7fffffff, ti6 = 0x7fffffff, ti7 = 0x7fffffff;
  int ti8 = 0x7fffffff;

  for (int tl = 0; tl < TPC; ++tl) {
    const bf16x8* ap = (const bf16x8*)(astb + (size_t)(t0 + tl) * TS);
    bf16x8 aH0 = ap[0 * 64 + lane], aH1 = ap[1 * 64 + lane], aH2 = ap[2 * 64 + lane];
    bf16x8 aM0 = ap[3 * 64 + lane], aM1 = ap[4 * 64 + lane], aM2 = ap[5 * 64 + lane];
    bf16x8 aL0 = ap[6 * 64 + lane], aL1 = ap[7 * 64 + lane], aL2 = ap[8 * 64 + lane];
    int mbase = (t0 + tl) * 16 + ((lane >> 4) << 2);
    float4 sqv = *(const float4*)(sqb + mbase);
    f32x4 acc0 = {0.f, 0.f, 0.f, 0.f}, acc1 = {0.f, 0.f, 0.f, 0.f};
    f32x4 acc2 = {0.f, 0.f, 0.f, 0.f}, acc3 = {0.f, 0.f, 0.f, 0.f};
    __builtin_amdgcn_s_setprio(1);
#pragma unroll
    for (int s = 0; s < 3; ++s) {
      bf16x8 aH = (s == 0) ? aH0 : (s == 1) ? aH1 : aH2;
      bf16x8 aM = (s == 0) ? aM0 : (s == 1) ? aM1 : aM2;
      bf16x8 aL = (s == 0) ? aL0 : (s == 1) ? aL1 : aL2;
      bf16x8 bH = bl[(0 + s) * 64 + lane];
      bf16x8 bM = bl[(3 + s) * 64 + lane];
      bf16x8 bL = bl[(6 + s) * 64 + lane];
      acc0 = __builtin_amdgcn_mfma_f32_16x16x32_bf16(aH, bH, acc0, 0, 0, 0);
      acc1 = __builtin_amdgcn_mfma_f32_16x16x32_bf16(aM, bH, acc1, 0, 0, 0);
      acc2 = __builtin_amdgcn_mfma_f32_16x16x32_bf16(aL, bH, acc2, 0, 0, 0);
      acc3 = __builtin_amdgcn_mfma_f32_16x16x32_bf16(aH, bM, acc3, 0, 0, 0);
      acc2 = __builtin_amdgcn_mfma_f32_16x16x32_bf16(aH, bL, acc2, 0, 0, 0);
      acc3 = __builtin_amdgcn_mfma_f32_16x16x32_bf16(aM, bM, acc3, 0, 0, 0);
    }
    __builtin_amdgcn_s_setprio(0);
#pragma unroll
    for (int r2 = 0; r2 < 4; ++r2) {
      float d = (((acc1[r2] + acc3[r2]) + acc2[r2]) + acc0[r2]) + sqv[r2];
      int m = mbase + r2;
      if (d < tv8) {                // strict <: equal keys keep earlier index
        tv8 = d; ti8 = m;
        CSWAP(tv7, ti7, tv8, ti8);
        CSWAP(tv6, ti6, tv7, ti7);
        CSWAP(tv5, ti5, tv6, ti6);
        CSWAP(tv4, ti4, tv5, ti5);
        CSWAP(tv3, ti3, tv4, ti4);
        CSWAP(tv2, ti2, tv3, ti3);
        CSWAP(tv1, ti1, tv2, ti2);
        CSWAP(tv0, ti0, tv1, ti1);
      }
    }
  }
  int g = lane >> 4;
  int n = tn * 16 + (lane & 15);
  size_t base = (((size_t)b * NLIST + (chunk * 4 + g)) * NP + n) * (size_t)KNN;
  pd[base + 0] = tv0; pi[base + 0] = ti0;
  pd[base + 1] = tv1; pi[base + 1] = ti1;
  pd[base + 2] = tv2; pi[base + 2] = ti2;
  pd[base + 3] = tv3; pi[base + 3] = ti3;
  pd[base + 4] = tv4; pi[base + 4] = ti4;
  pd[base + 5] = tv5; pi[base + 5] = ti5;
  pd[base + 6] = tv6; pi[base + 6] = ti6;
  pd[base + 7] = tv7; pi[base + 7] = ti7;
  pd[base + 8] = tv8; pi[base + 8] = ti8;
}

// ---------- K4b v2: two-phase 4-wide k-way merge of 16 SORTED top-9 lists.
#define ARGMIN4(e0, j0, e1, j1, e2, j2, e3, j3, DW, IW, W0, W1, W2, W3) \
  bool _l01 = ((e0) < (e1)) || ((e0) == (e1) && (j0) < (j1)); \
  float _da = _l01 ? (e0) : (e1); int _ia = _l01 ? (j0) : (j1); \
  bool _l23 = ((e2) < (e3)) || ((e2) == (e3) && (j2) < (j3)); \
  float _db = _l23 ? (e2) : (e3); int _ib = _l23 ? (j2) : (j3); \
  bool _lab = (_da < _db) || (_da == _db && _ia < _ib); \
  float DW = _lab ? _da : _db; int IW = _lab ? _ia : _ib; \
  bool W0 = _lab && _l01, W1 = _lab && !_l01, W2 = !_lab && _l23, W3 = !_lab && !_l23;

__global__ __launch_bounds__(256) void k4b_merge(const float* __restrict__ pd,
    const int* __restrict__ pi, int* __restrict__ nidx) {
  __shared__ float ld_d[256][KNN];
  __shared__ int   ld_i[256][KNN];
  int tid = threadIdx.x;
  int gid = blockIdx.x * 256 + tid;
  int q = gid >> 2, s = gid & 3;
  int b = q / NP, n = q - b * NP;
  size_t b0 = (((size_t)b * NLIST + (s * 4 + 0)) * NP + n) * (size_t)KNN;
  size_t b1 = (((size_t)b * NLIST + (s * 4 + 1)) * NP + n) * (size_t)KNN;
  size_t b2 = (((size_t)b * NLIST + (s * 4 + 2)) * NP + n) * (size_t)KNN;
  size_t b3 = (((size_t)b * NLIST + (s * 4 + 3)) * NP + n) * (size_t)KNN;
  int p0 = 0, p1 = 0, p2 = 0, p3 = 0;
  float d0 = pd[b0], d1 = pd[b1], d2 = pd[b2], d3 = pd[b3];
  int i0 = pi[b0], i1 = pi[b1], i2 = pi[b2], i3 = pi[b3];
#pragma unroll
  for (int k = 0; k < KNN; ++k) {
    ARGMIN4(d0, i0, d1, i1, d2, i2, d3, i3, dw, iw, w0, w1, w2, w3);
    ld_d[tid][k] = dw; ld_i[tid][k] = iw;
    if (w0) { ++p0; bool ok = p0 < KNN; d0 = ok ? pd[b0 + p0] : FLT_MAX; i0 = ok ? pi[b0 + p0] : 0x7fffffff; }
    if (w1) { ++p1; bool ok = p1 < KNN; d1 = ok ? pd[b1 + p1] : FLT_MAX; i1 = ok ? pi[b1 + p1] : 0x7fffffff; }
    if (w2) { ++p2; bool ok = p2 < KNN; d2 = ok ? pd[b2 + p2] : FLT_MAX; i2 = ok ? pi[b2 + p2] : 0x7fffffff; }
    if (w3) { ++p3; bool ok = p3 < KNN; d3 = ok ? pd[b3 + p3] : FLT_MAX; i3 = ok ? pi[b3 + p3] : 0x7fffffff; }
  }
  __syncthreads();
  if (s == 0) {
    int h0 = 0, h1 = 0, h2 = 0, h3 = 0;
    float e0 = ld_d[tid][0], e1 = ld_d[tid + 1][0], e2 = ld_d[tid + 2][0], e3 = ld_d[tid + 3][0];
    int j0 = ld_i[tid][0], j1 = ld_i[tid + 1][0], j2 = ld_i[tid + 2][0], j3 = ld_i[tid + 3][0];
    int* op = nidx + (size_t)q * KNN;
#pragma unroll
    for (int k = 0; k < KNN; ++k) {
      ARGMIN4(e0, j0, e1, j1, e2, j2, e3, j3, dw, iw, w0, w1, w2, w3);
      op[k] = iw;
      if (w0) { ++h0; bool ok = h0 < KNN; e0 = ok ? ld_d[tid][h0] : FLT_MAX; j0 = ok ? ld_i[tid][h0] : 0x7fffffff; }
      if (w1) { ++h1; bool ok = h1 < KNN; e1 = ok ? ld_d[tid + 1][h1] : FLT_MAX; j1 = ok ? ld_i[tid + 1][h1] : 0x7fffffff; }
      if (w2) { ++h2; bool ok = h2 < KNN; e2 = ok ? ld_d[tid + 2][h2] : FLT_MAX; j2 = ok ? ld_i[tid + 2][h2] : 0x7fffffff; }
      if (w3) { ++h3; bool ok = h3 < KNN; e3 = ok ? ld_d[tid + 3][h3] : FLT_MAX; j3 = ok ? ld_i[tid + 3][h3] : 0x7fffffff; }
    }
  }
}

// ---------- K5: a = (W1-W2)·f + gb ; u = W2·f
__global__ __launch_bounds__(256) void k5_au(const float* __restrict__ feats,
    const float* __restrict__ gw, const float* __restrict__ gb,
    float* __restrict__ a, float* __restrict__ u) {
  __shared__ float sf[32][97];
  __shared__ float swc[64 * C2];
  int b = blockIdx.y, n0 = blockIdx.x * 32;
  int tid = threadIdx.x;
  for (int i = tid; i < 32 * CHN; i += 256) {
    int nn = i / CHN, c = i - nn * CHN;
    sf[nn][c] = feats[((size_t)b * NP + n0 + nn) * CHN + c];
  }
  int nn = tid & 31, sub = tid >> 5;
  for (int oc = 0; oc < 3; ++oc) {
    __syncthreads();
    for (int i = tid; i < 64 * C2; i += 256) swc[i] = gw[(size_t)(oc * 64) * C2 + i];
    __syncthreads();
    float accA[8], accU[8];
#pragma unroll
    for (int j = 0; j < 8; ++j) { accA[j] = 0.f; accU[j] = 0.f; }
    for (int c = 0; c < CHN; ++c) {
      float f = sf[nn][c];
#pragma unroll
      for (int j = 0; j < 8; ++j) {
        float w1 = swc[(sub * 8 + j) * C2 + c];
        float wv2 = swc[(sub * 8 + j) * C2 + 96 + c];
        accA[j] = fmaf(w1 - wv2, f, accA[j]);
        accU[j] = fmaf(wv2, f, accU[j]);
      }
    }
    size_t row = ((size_t)b * NP + n0 + nn) * C2;
#pragma unroll
    for (int j = 0; j < 8; ++j) {
      int o = oc * 64 + sub * 8 + j;
      a[row + o] = accA[j] + gb[o];
      u[row + o] = accU[j];
    }
  }
}

// ---------- K6: agg = relu(a + max_k u[idx_k]); ol = fc2_w·agg + fc2_b
__global__ __launch_bounds__(256) void k6_edge(const float* __restrict__ a,
    const float* __restrict__ u, const int* __restrict__ nidx,
    const float* __restrict__ w2, const float* __restrict__ b2, float* __restrict__ ol) {
  __shared__ float sagg[32][193];
  int b = blockIdx.y, n0 = blockIdx.x * 32;
  int tid = threadIdx.x;
  int wv = tid >> 6, ln = tid & 63;
  for (int p = 0; p < 8; ++p) {
    int nn = wv * 8 + p;
    size_t row = (size_t)b * NP + n0 + nn;
    const int* ip = nidx + row * KNN;
    int idx[KNN];
#pragma unroll
    for (int k = 0; k < KNN; ++k) idx[k] = ip[k];
#pragma unroll
    for (int oo = 0; oo < 3; ++oo) {
      int o = oo * 64 + ln;
      float umax = -FLT_MAX;
#pragma unroll
      for (int k = 0; k < KNN; ++k)
        umax = fmaxf(umax, u[((size_t)b * NP + idx[k]) * C2 + o]);
      float av = a[row * C2 + o];
      sagg[nn][o] = fmaxf(av + umax, 0.f);
    }
  }
  __syncthreads();
  int nn = tid & 31, sub = tid >> 5;
  for (int j = 0; j < 12; ++j) {
    int o2 = sub + 8 * j;
    float acc = b2[o2];
    for (int o = 0; o < C2; ++o) acc = fmaf(w2[o2 * C2 + o], sagg[nn][o], acc);
    ol[((size_t)b * CHN + o2) * NP + n0 + nn] = acc;
  }
}

// ---------- K8: out = (ol - mean)*rstd + shortcut
__global__ __launch_bounds__(256) void k8_final(const float* __restrict__ ol,
    const float* __restrict__ stat, const float* __restrict__ x, float* __restrict__ out) {
  int i = blockIdx.x * 256 + threadIdx.x;
  int bo = i / NP;
  float m = stat[bo * 2], r = stat[bo * 2 + 1];
  out[i] = fmaf(ol[i] - m, r, x[i]);
}

extern "C" void kernel_launch(void* const* d_in, const int* in_sizes, int n_in,
                              void* d_out, int out_size, void* d_ws, size_t ws_size,
                              hipStream_t stream) {
  const float* x   = (const float*)d_in[0];
  const float* f1w = (const float*)d_in[1];
  const float* f1b = (const float*)d_in[2];
  const float* gw  = (const float*)d_in[3];
  const float* gb  = (const float*)d_in[4];
  const float* f2w = (const float*)d_in[5];
  const float* f2b = (const float*)d_in[6];
  float* out = (float*)d_out;
  char* ws = (char*)d_ws;

  // u needs BQ*NP*C2*4 = 19.27 MB. Round-14 bug: OFF_U = OFF_AST+SZ_STR gave it
  // only 14.45 MB -> tail overlapped ol. FIX: OFF_U = OFF_AST (ast dead after
  // k4; [OFF_AST, OFF_NRM) = 28.9 MB holds it).
  constexpr size_t SZ_MAT = (size_t)BQ * CHN * NP * 4;           // 9,633,792
  constexpr size_t SZ_STR = (size_t)BQ * NT * NFRAG * 512 * 2;   // 14,450,688
  constexpr size_t SZ_PL  = (size_t)BQ * NLIST * NP * KNN * 4;   // 14,450,688
  constexpr size_t OFF_H   = 0;
  constexpr size_t OFF_PD  = 0;
  constexpr size_t OFF_PI  = OFF_PD + SZ_PL;
  constexpr size_t OFF_A   = 0;
  constexpr size_t OFF_AST = 2 * SZ_PL;
  constexpr size_t OFF_U   = OFF_AST;            // 28.9 MB region, holds 19.3 MB
  constexpr size_t OFF_NRM = OFF_AST + 2 * SZ_STR;
  constexpr size_t OFF_OL  = OFF_NRM;
  constexpr size_t OFF_FE  = OFF_NRM + SZ_MAT;
  constexpr size_t OFF_SQ  = OFF_FE + SZ_MAT;
  constexpr size_t OFF_ST1 = OFF_SQ + (size_t)BQ * NP * 4;
  constexpr size_t OFF_ST2 = OFF_ST1 + (size_t)BQ * CHN * 2 * 4;
  constexpr size_t OFF_NI  = OFF_ST2 + (size_t)BQ * CHN * 2 * 4;

  float* h   = (float*)(ws + OFF_H);
  float* fe  = (float*)(ws + OFF_FE);
  float* nrm = (float*)(ws + OFF_NRM);
  float* sq  = (float*)(ws + OFF_SQ);
  float* st1 = (float*)(ws + OFF_ST1);
  float* st2 = (float*)(ws + OFF_ST2);
  int*   ni  = (int*)(ws + OFF_NI);
  ushort* ast = (ushort*)(ws + OFF_AST);
  float* pd  = (float*)(ws + OFF_PD);
  int*   pi  = (int*)(ws + OFF_PI);
  float* aA  = (float*)(ws + OFF_A);
  float* uU  = (float*)(ws + OFF_U);
  float* ol  = (float*)(ws + OFF_OL);

  k1_conv1<<<dim3(NP / 64, BQ), 256, 0, stream>>>(x, f1w, f1b, h);
  k2_stats<<<dim3(BQ * CHN), 256, 0, stream>>>(h, st1);
  k3_norm<<<dim3(NP / 32, BQ), 256, 0, stream>>>(h, st1, fe, nrm, sq);
  k3b_prep<<<dim3(NT, BQ), 256, 0, stream>>>(nrm, ast);
  k4_mfma<<<dim3((NT / 4) * MCH * BQ), 256, 0, stream>>>(ast, sq, pd, pi);
  k4b_merge<<<dim3(BQ * NP * 4 / 256), 256, 0, stream>>>(pd, pi, ni);
  k5_au<<<dim3(NP / 32, BQ), 256, 0, stream>>>(fe, gw, gb, aA, uU);
  k6_edge<<<dim3(NP / 32, BQ), 256, 0, stream>>>(aA, uU, ni, f2w, f2b, ol);
  k2_stats<<<dim3(BQ * CHN), 256, 0, stream>>>(ol, st2);
  k8_final<<<dim3(BQ * CHN * NP / 256), 256, 0, stream>>>(ol, st2, x, out);
}

// Round 16
// 394.007 us; speedup vs baseline: 1.4716x; 1.0514x over previous
//
#include <hip/hip_runtime.h>
#include <float.h>

#define BQ 8
#define CHN 96
#define NP 3136
#define KNN 9
#define C2 192
#define NT 196        // 16-wide tiles along n/m
#define MCH 4         // m-chunks
#define TPC (NT/MCH)  // 49 tiles per chunk
#define NFRAG 9       // 3-way split: h0,h1,h2,m0,m1,m2,l0,l1,l2
#define NLIST 16      // partial top-9 lists per query (4 m-chunks x 4 lane-groups)

typedef __attribute__((ext_vector_type(8))) short bf16x8;
typedef __attribute__((ext_vector_type(4))) float f32x4;
typedef __attribute__((ext_vector_type(4))) unsigned int u32x4;

__device__ inline ushort f2bf(float x) {            // round-to-nearest-even
  unsigned u = __float_as_uint(x);
  return (ushort)((u + 0x7FFFu + ((u >> 16) & 1u)) >> 16);
}
__device__ inline float bf2f(ushort h) { return __uint_as_float((unsigned)h << 16); }

// ---------- K1: h[b][o][n] = sum_c fc1_w[o][c] * x[b][c][n] + fc1_b[o]
__global__ __launch_bounds__(256) void k1_conv1(const float* __restrict__ x,
    const float* __restrict__ w, const float* __restrict__ bias, float* __restrict__ h) {
  __shared__ float sw[CHN * CHN];
  __shared__ float sx[CHN][64];
  int b = blockIdx.y;
  int n0 = blockIdx.x * 64;
  int tid = threadIdx.x;
  for (int i = tid; i < CHN * CHN; i += 256) sw[i] = w[i];
  const float* xb = x + (size_t)b * CHN * NP + n0;
  for (int i = tid; i < CHN * 64; i += 256) {
    int c = i >> 6, nn = i & 63;
    sx[c][nn] = xb[(size_t)c * NP + nn];
  }
  __syncthreads();
  int nn = tid & 63;
  int o0 = (tid >> 6) * 24;
  float acc[24];
#pragma unroll
  for (int j = 0; j < 24; ++j) acc[j] = 0.f;
  for (int c = 0; c < CHN; ++c) {
    float xv = sx[c][nn];
#pragma unroll
    for (int j = 0; j < 24; ++j) acc[j] = fmaf(sw[(o0 + j) * CHN + c], xv, acc[j]);
  }
  float* hb = h + (size_t)b * CHN * NP + n0;
#pragma unroll
  for (int j = 0; j < 24; ++j) hb[(size_t)(o0 + j) * NP + nn] = acc[j] + bias[o0 + j];
}

// ---------- K2/K7: per-(b,channel) mean + rstd
__global__ __launch_bounds__(256) void k2_stats(const float* __restrict__ src,
                                                float* __restrict__ stat) {
  int bo = blockIdx.x;
  const float* p = src + (size_t)bo * NP;
  float s = 0.f, ss = 0.f;
  for (int i = threadIdx.x; i < NP; i += 256) { float v = p[i]; s += v; ss = fmaf(v, v, ss); }
#pragma unroll
  for (int off = 32; off; off >>= 1) { s += __shfl_down(s, off); ss += __shfl_down(ss, off); }
  __shared__ float as[4], ass[4];
  int wv = threadIdx.x >> 6;
  if ((threadIdx.x & 63) == 0) { as[wv] = s; ass[wv] = ss; }
  __syncthreads();
  if (threadIdx.x == 0) {
    float S = as[0] + as[1] + as[2] + as[3];
    float SS = ass[0] + ass[1] + ass[2] + ass[3];
    float mean = S * (1.f / NP);
    float var = SS * (1.f / NP) - mean * mean;
    if (var < 0.f) var = 0.f;
    stat[bo * 2] = mean;
    stat[bo * 2 + 1] = 1.f / sqrtf(var + 1e-5f);
  }
}

// ---------- K3: normalize h -> feats[b][n][c]; nrm = feats/max(||f||,eps); sq = sum(nrm^2)
__global__ __launch_bounds__(256) void k3_norm(const float* __restrict__ h,
    const float* __restrict__ stat, float* __restrict__ feats, float* __restrict__ nrm,
    float* __restrict__ sq) {
  __shared__ float tile[CHN][33];
  __shared__ float part[8][32];
  __shared__ float sinv[32];
  int b = blockIdx.y, n0 = blockIdx.x * 32;
  int tid = threadIdx.x;
  for (int i = tid; i < CHN * 32; i += 256) {
    int c = i >> 5, nn = i & 31;
    float m = stat[(b * CHN + c) * 2];
    float r = stat[(b * CHN + c) * 2 + 1];
    tile[c][nn] = (h[((size_t)(b * CHN + c)) * NP + n0 + nn] - m) * r;
  }
  __syncthreads();
  int nn = tid & 31, sub = tid >> 5;
  float ss = 0.f;
#pragma unroll
  for (int j = 0; j < 12; ++j) { float f = tile[sub * 12 + j][nn]; ss = fmaf(f, f, ss); }
  part[sub][nn] = ss;
  __syncthreads();
  if (tid < 32) {
    float S = 0.f;
#pragma unroll
    for (int w = 0; w < 8; ++w) S += part[w][tid];
    float norm = sqrtf(S);
    sinv[tid] = 1.f / fmaxf(norm, 1e-12f);
  }
  __syncthreads();
  float inv = sinv[nn];
  float ss2 = 0.f;
#pragma unroll
  for (int j = 0; j < 12; ++j) { float f = tile[sub * 12 + j][nn] * inv; ss2 = fmaf(f, f, ss2); }
  part[sub][nn] = ss2;
  __syncthreads();
  if (tid < 32) {
    float S = 0.f;
#pragma unroll
    for (int w = 0; w < 8; ++w) S += part[w][tid];
    sq[(size_t)b * NP + n0 + tid] = S;
  }
  for (int i = tid; i < 32 * CHN; i += 256) {
    int nn2 = i / CHN, c = i - nn2 * CHN;
    float f = tile[c][nn2];
    size_t o = ((size_t)b * NP + n0 + nn2) * CHN + c;
    feats[o] = f;
    nrm[o] = f * sinv[nn2];
  }
}

// ---------- K3b: build MFMA A-operand stream only (3-way bf16 split).
__global__ __launch_bounds__(256) void k3b_prep(const float* __restrict__ nrm,
    ushort* __restrict__ ast) {
  int b = blockIdx.y, t = blockIdx.x;
  int tid = threadIdx.x;
  const float* nb = nrm + (size_t)b * NP * CHN;
  ushort* ao = ast + (((size_t)b * NT + t) * NFRAG) * 512;
  for (int e = tid; e < NFRAG * 512; e += 256) {
    int f = e >> 9, l = (e >> 3) & 63, j = e & 7;
    int part = f / 3, sl = f - part * 3;
    int c = sl * 32 + (l >> 4) * 8 + j;
    int m = t * 16 + (l & 15);
    float xv = nb[(size_t)m * CHN + c];
    ushort hh = f2bf(xv);
    float rm = xv - bf2f(hh);          // exact
    ushort md = f2bf(rm);
    ushort v = (part == 0) ? hh : (part == 1) ? md : f2bf(rm - bf2f(md));
    ao[e] = v;
  }
}

// ---------- K4 v8 (round-15 proven, 174us): XCD-pinned swizzle, in-register
// B derivation (exact -2x), setprio, wave-private-LDS B, named tv/ti.
#define CSWAP(vI, iI, vJ, iJ) do { \
    bool _s = (vJ) < (vI); \
    float _fa = _s ? (vJ) : (vI); float _fb = _s ? (vI) : (vJ); \
    int _ia = _s ? (iJ) : (iI); int _ib = _s ? (iI) : (iJ); \
    (vI) = _fa; (vJ) = _fb; (iI) = _ia; (iJ) = _ib; \
  } while (0)

__device__ inline bf16x8 neg2x(bf16x8 v) {          // exact -2*x on 8 packed bf16
  u32x4 w = __builtin_bit_cast(u32x4, v);
#pragma unroll
  for (int i = 0; i < 4; ++i) w[i] = (w[i] ^ 0x80008000u) + 0x00800080u;
  return __builtin_bit_cast(bf16x8, w);
}

__global__ __launch_bounds__(256) void k4_mfma(
    const ushort* __restrict__ ast, const float* __restrict__ sq,
    float* __restrict__ pd, int* __restrict__ pi) {
  int id = blockIdx.x;
  int g8 = id & 7, r = id >> 3;
  int ng = r % 49, gd = r / 49;          // gd in 0..3
  int group = gd * 8 + g8;               // 0..31, bijective
  int chunk = group & 3, b = group >> 2;
  int wave = threadIdx.x >> 6, lane = threadIdx.x & 63;
  int tn = ng * 4 + wave;

  __shared__ ushort lds_b[4 * NFRAG * 512];   // 36,864 B, wave-private regions
  {
    const bf16x8* bp = (const bf16x8*)(ast + (((size_t)b * NT + tn) * NFRAG) * 512);
    bf16x8* dst = (bf16x8*)(lds_b + wave * (NFRAG * 512));
#pragma unroll
    for (int f = 0; f < NFRAG; ++f) dst[f * 64 + lane] = neg2x(bp[f * 64 + lane]);
  }
  const bf16x8* bl = (const bf16x8*)(lds_b + wave * (NFRAG * 512));

  const float* sqb = sq + (size_t)b * NP;
  const ushort* astb = ast + ((size_t)b * NT) * (NFRAG * 512);
  int t0 = chunk * TPC;
  const size_t TS = (size_t)NFRAG * 512;

  float tv0 = FLT_MAX, tv1 = FLT_MAX, tv2 = FLT_MAX, tv3 = FLT_MAX, tv4 = FLT_MAX;
  float tv5 = FLT_MAX, tv6 = FLT_MAX, tv7 = FLT_MAX, tv8 = FLT_MAX;
  int ti0 = 0x7fffffff, ti1 = 0x7fffffff, ti2 = 0x7fffffff, ti3 = 0x7fffffff;
  int ti4 = 0x7fffffff, ti5 = 0x7fffffff, ti6 = 0x7fffffff, ti7 = 0x7fffffff;
  int ti8 = 0x7fffffff;

  for (int tl = 0; tl < TPC; ++tl) {
    const bf16x8* ap = (const bf16x8*)(astb + (size_t)(t0 + tl) * TS);
    bf16x8 aH0 = ap[0 * 64 + lane], aH1 = ap[1 * 64 + lane], aH2 = ap[2 * 64 + lane];
    bf16x8 aM0 = ap[3 * 64 + lane], aM1 = ap[4 * 64 + lane], aM2 = ap[5 * 64 + lane];
    bf16x8 aL0 = ap[6 * 64 + lane], aL1 = ap[7 * 64 + lane], aL2 = ap[8 * 64 + lane];
    int mbase = (t0 + tl) * 16 + ((lane >> 4) << 2);
    float4 sqv = *(const float4*)(sqb + mbase);
    f32x4 acc0 = {0.f, 0.f, 0.f, 0.f}, acc1 = {0.f, 0.f, 0.f, 0.f};
    f32x4 acc2 = {0.f, 0.f, 0.f, 0.f}, acc3 = {0.f, 0.f, 0.f, 0.f};
    __builtin_amdgcn_s_setprio(1);
#pragma unroll
    for (int s = 0; s < 3; ++s) {
      bf16x8 aH = (s == 0) ? aH0 : (s == 1) ? aH1 : aH2;
      bf16x8 aM = (s == 0) ? aM0 : (s == 1) ? aM1 : aM2;
      bf16x8 aL = (s == 0) ? aL0 : (s == 1) ? aL1 : aL2;
      bf16x8 bH = bl[(0 + s) * 64 + lane];
      bf16x8 bM = bl[(3 + s) * 64 + lane];
      bf16x8 bL = bl[(6 + s) * 64 + lane];
      acc0 = __builtin_amdgcn_mfma_f32_16x16x32_bf16(aH, bH, acc0, 0, 0, 0);
      acc1 = __builtin_amdgcn_mfma_f32_16x16x32_bf16(aM, bH, acc1, 0, 0, 0);
      acc2 = __builtin_amdgcn_mfma_f32_16x16x32_bf16(aL, bH, acc2, 0, 0, 0);
      acc3 = __builtin_amdgcn_mfma_f32_16x16x32_bf16(aH, bM, acc3, 0, 0, 0);
      acc2 = __builtin_amdgcn_mfma_f32_16x16x32_bf16(aH, bL, acc2, 0, 0, 0);
      acc3 = __builtin_amdgcn_mfma_f32_16x16x32_bf16(aM, bM, acc3, 0, 0, 0);
    }
    __builtin_amdgcn_s_setprio(0);
#pragma unroll
    for (int r2 = 0; r2 < 4; ++r2) {
      float d = (((acc1[r2] + acc3[r2]) + acc2[r2]) + acc0[r2]) + sqv[r2];
      int m = mbase + r2;
      if (d < tv8) {                // strict <: equal keys keep earlier index
        tv8 = d; ti8 = m;
        CSWAP(tv7, ti7, tv8, ti8);
        CSWAP(tv6, ti6, tv7, ti7);
        CSWAP(tv5, ti5, tv6, ti6);
        CSWAP(tv4, ti4, tv5, ti5);
        CSWAP(tv3, ti3, tv4, ti4);
        CSWAP(tv2, ti2, tv3, ti3);
        CSWAP(tv1, ti1, tv2, ti2);
        CSWAP(tv0, ti0, tv1, ti1);
      }
    }
  }
  int g = lane >> 4;
  int n = tn * 16 + (lane & 15);
  size_t base = (((size_t)b * NLIST + (chunk * 4 + g)) * NP + n) * (size_t)KNN;
  pd[base + 0] = tv0; pi[base + 0] = ti0;
  pd[base + 1] = tv1; pi[base + 1] = ti1;
  pd[base + 2] = tv2; pi[base + 2] = ti2;
  pd[base + 3] = tv3; pi[base + 3] = ti3;
  pd[base + 4] = tv4; pi[base + 4] = ti4;
  pd[base + 5] = tv5; pi[base + 5] = ti5;
  pd[base + 6] = tv6; pi[base + 6] = ti6;
  pd[base + 7] = tv7; pi[base + 7] = ti7;
  pd[base + 8] = tv8; pi[base + 8] = ti8;
}

// ---------- K4b v2: two-phase 4-wide k-way merge of 16 SORTED top-9 lists.
#define ARGMIN4(e0, j0, e1, j1, e2, j2, e3, j3, DW, IW, W0, W1, W2, W3) \
  bool _l01 = ((e0) < (e1)) || ((e0) == (e1) && (j0) < (j1)); \
  float _da = _l01 ? (e0) : (e1); int _ia = _l01 ? (j0) : (j1); \
  bool _l23 = ((e2) < (e3)) || ((e2) == (e3) && (j2) < (j3)); \
  float _db = _l23 ? (e2) : (e3); int _ib = _l23 ? (j2) : (j3); \
  bool _lab = (_da < _db) || (_da == _db && _ia < _ib); \
  float DW = _lab ? _da : _db; int IW = _lab ? _ia : _ib; \
  bool W0 = _lab && _l01, W1 = _lab && !_l01, W2 = !_lab && _l23, W3 = !_lab && !_l23;

__global__ __launch_bounds__(256) void k4b_merge(const float* __restrict__ pd,
    const int* __restrict__ pi, int* __restrict__ nidx) {
  __shared__ float ld_d[256][KNN];
  __shared__ int   ld_i[256][KNN];
  int tid = threadIdx.x;
  int gid = blockIdx.x * 256 + tid;
  int q = gid >> 2, s = gid & 3;
  int b = q / NP, n = q - b * NP;
  size_t b0 = (((size_t)b * NLIST + (s * 4 + 0)) * NP + n) * (size_t)KNN;
  size_t b1 = (((size_t)b * NLIST + (s * 4 + 1)) * NP + n) * (size_t)KNN;
  size_t b2 = (((size_t)b * NLIST + (s * 4 + 2)) * NP + n) * (size_t)KNN;
  size_t b3 = (((size_t)b * NLIST + (s * 4 + 3)) * NP + n) * (size_t)KNN;
  int p0 = 0, p1 = 0, p2 = 0, p3 = 0;
  float d0 = pd[b0], d1 = pd[b1], d2 = pd[b2], d3 = pd[b3];
  int i0 = pi[b0], i1 = pi[b1], i2 = pi[b2], i3 = pi[b3];
#pragma unroll
  for (int k = 0; k < KNN; ++k) {
    ARGMIN4(d0, i0, d1, i1, d2, i2, d3, i3, dw, iw, w0, w1, w2, w3);
    ld_d[tid][k] = dw; ld_i[tid][k] = iw;
    if (w0) { ++p0; bool ok = p0 < KNN; d0 = ok ? pd[b0 + p0] : FLT_MAX; i0 = ok ? pi[b0 + p0] : 0x7fffffff; }
    if (w1) { ++p1; bool ok = p1 < KNN; d1 = ok ? pd[b1 + p1] : FLT_MAX; i1 = ok ? pi[b1 + p1] : 0x7fffffff; }
    if (w2) { ++p2; bool ok = p2 < KNN; d2 = ok ? pd[b2 + p2] : FLT_MAX; i2 = ok ? pi[b2 + p2] : 0x7fffffff; }
    if (w3) { ++p3; bool ok = p3 < KNN; d3 = ok ? pd[b3 + p3] : FLT_MAX; i3 = ok ? pi[b3 + p3] : 0x7fffffff; }
  }
  __syncthreads();
  if (s == 0) {
    int h0 = 0, h1 = 0, h2 = 0, h3 = 0;
    float e0 = ld_d[tid][0], e1 = ld_d[tid + 1][0], e2 = ld_d[tid + 2][0], e3 = ld_d[tid + 3][0];
    int j0 = ld_i[tid][0], j1 = ld_i[tid + 1][0], j2 = ld_i[tid + 2][0], j3 = ld_i[tid + 3][0];
    int* op = nidx + (size_t)q * KNN;
#pragma unroll
    for (int k = 0; k < KNN; ++k) {
      ARGMIN4(e0, j0, e1, j1, e2, j2, e3, j3, dw, iw, w0, w1, w2, w3);
      op[k] = iw;
      if (w0) { ++h0; bool ok = h0 < KNN; e0 = ok ? ld_d[tid][h0] : FLT_MAX; j0 = ok ? ld_i[tid][h0] : 0x7fffffff; }
      if (w1) { ++h1; bool ok = h1 < KNN; e1 = ok ? ld_d[tid + 1][h1] : FLT_MAX; j1 = ok ? ld_i[tid + 1][h1] : 0x7fffffff; }
      if (w2) { ++h2; bool ok = h2 < KNN; e2 = ok ? ld_d[tid + 2][h2] : FLT_MAX; j2 = ok ? ld_i[tid + 2][h2] : 0x7fffffff; }
      if (w3) { ++h3; bool ok = h3 < KNN; e3 = ok ? ld_d[tid + 3][h3] : FLT_MAX; j3 = ok ? ld_i[tid + 3][h3] : 0x7fffffff; }
    }
  }
}

// ---------- K5 v2: a = (W1-W2)·f + gb ; u = W2·f  — float4-vectorized LDS
// reads (round-15 audit: 4608 scalar ds_read_b32/thread was LDS-issue-bound).
// FMA accumulation order per acc is IDENTICAL to v1 (c ascending) -> bit-exact.
__global__ __launch_bounds__(256) void k5_au(const float* __restrict__ feats,
    const float* __restrict__ gw, const float* __restrict__ gb,
    float* __restrict__ a, float* __restrict__ u) {
  __shared__ float sf[32][100];      // row = 400 B, 16B-aligned
  __shared__ float swc[64 * C2];
  int b = blockIdx.y, n0 = blockIdx.x * 32;
  int tid = threadIdx.x;
  for (int i = tid; i < 32 * CHN; i += 256) {
    int nn = i / CHN, c = i - nn * CHN;
    sf[nn][c] = feats[((size_t)b * NP + n0 + nn) * CHN + c];
  }
  int nn = tid & 31, sub = tid >> 5;
  for (int oc = 0; oc < 3; ++oc) {
    __syncthreads();
    for (int i = tid; i < 64 * C2; i += 256) swc[i] = gw[(size_t)(oc * 64) * C2 + i];
    __syncthreads();
    float accA[8], accU[8];
#pragma unroll
    for (int j = 0; j < 8; ++j) { accA[j] = 0.f; accU[j] = 0.f; }
    for (int c4 = 0; c4 < CHN; c4 += 4) {
      float4 fv = *(const float4*)&sf[nn][c4];
#pragma unroll
      for (int j = 0; j < 8; ++j) {
        const float* wr = &swc[(sub * 8 + j) * C2];
        float4 w1v = *(const float4*)(wr + c4);
        float4 w2v = *(const float4*)(wr + 96 + c4);
        accA[j] = fmaf(w1v.x - w2v.x, fv.x, accA[j]);
        accU[j] = fmaf(w2v.x, fv.x, accU[j]);
        accA[j] = fmaf(w1v.y - w2v.y, fv.y, accA[j]);
        accU[j] = fmaf(w2v.y, fv.y, accU[j]);
        accA[j] = fmaf(w1v.z - w2v.z, fv.z, accA[j]);
        accU[j] = fmaf(w2v.z, fv.z, accU[j]);
        accA[j] = fmaf(w1v.w - w2v.w, fv.w, accA[j]);
        accU[j] = fmaf(w2v.w, fv.w, accU[j]);
      }
    }
    size_t row = ((size_t)b * NP + n0 + nn) * C2;
    int ob = oc * 64 + sub * 8;
    float4 a0 = {accA[0] + gb[ob + 0], accA[1] + gb[ob + 1],
                 accA[2] + gb[ob + 2], accA[3] + gb[ob + 3]};
    float4 a1 = {accA[4] + gb[ob + 4], accA[5] + gb[ob + 5],
                 accA[6] + gb[ob + 6], accA[7] + gb[ob + 7]};
    float4 u0 = {accU[0], accU[1], accU[2], accU[3]};
    float4 u1 = {accU[4], accU[5], accU[6], accU[7]};
    *(float4*)&a[row + ob] = a0;
    *(float4*)&a[row + ob + 4] = a1;
    *(float4*)&u[row + ob] = u0;
    *(float4*)&u[row + ob + 4] = u1;
  }
}

// ---------- K6 v2: agg = relu(a + max_k u[idx_k]); ol = fc2_w·agg + fc2_b
// GEMM phase float4-vectorized (sagg + w2); accumulation order preserved.
__global__ __launch_bounds__(256) void k6_edge(const float* __restrict__ a,
    const float* __restrict__ u, const int* __restrict__ nidx,
    const float* __restrict__ w2, const float* __restrict__ b2, float* __restrict__ ol) {
  __shared__ float sagg[32][196];    // row = 784 B, 16B-aligned
  int b = blockIdx.y, n0 = blockIdx.x * 32;
  int tid = threadIdx.x;
  int wv = tid >> 6, ln = tid & 63;
  for (int p = 0; p < 8; ++p) {
    int nn = wv * 8 + p;
    size_t row = (size_t)b * NP + n0 + nn;
    const int* ip = nidx + row * KNN;
    int idx[KNN];
#pragma unroll
    for (int k = 0; k < KNN; ++k) idx[k] = ip[k];
#pragma unroll
    for (int oo = 0; oo < 3; ++oo) {
      int o = oo * 64 + ln;
      float umax = -FLT_MAX;
#pragma unroll
      for (int k = 0; k < KNN; ++k)
        umax = fmaxf(umax, u[((size_t)b * NP + idx[k]) * C2 + o]);
      float av = a[row * C2 + o];
      sagg[nn][o] = fmaxf(av + umax, 0.f);
    }
  }
  __syncthreads();
  int nn = tid & 31, sub = tid >> 5;
  for (int j = 0; j < 12; ++j) {
    int o2 = sub + 8 * j;
    float acc = b2[o2];
    const float* wr = w2 + (size_t)o2 * C2;
    for (int o4 = 0; o4 < C2; o4 += 4) {
      float4 wv4 = *(const float4*)(wr + o4);
      float4 sv = *(const float4*)&sagg[nn][o4];
      acc = fmaf(wv4.x, sv.x, acc);
      acc = fmaf(wv4.y, sv.y, acc);
      acc = fmaf(wv4.z, sv.z, acc);
      acc = fmaf(wv4.w, sv.w, acc);
    }
    ol[((size_t)b * CHN + o2) * NP + n0 + nn] = acc;
  }
}

// ---------- K8: out = (ol - mean)*rstd + shortcut
__global__ __launch_bounds__(256) void k8_final(const float* __restrict__ ol,
    const float* __restrict__ stat, const float* __restrict__ x, float* __restrict__ out) {
  int i = blockIdx.x * 256 + threadIdx.x;
  int bo = i / NP;
  float m = stat[bo * 2], r = stat[bo * 2 + 1];
  out[i] = fmaf(ol[i] - m, r, x[i]);
}

extern "C" void kernel_launch(void* const* d_in, const int* in_sizes, int n_in,
                              void* d_out, int out_size, void* d_ws, size_t ws_size,
                              hipStream_t stream) {
  const float* x   = (const float*)d_in[0];
  const float* f1w = (const float*)d_in[1];
  const float* f1b = (const float*)d_in[2];
  const float* gw  = (const float*)d_in[3];
  const float* gb  = (const float*)d_in[4];
  const float* f2w = (const float*)d_in[5];
  const float* f2b = (const float*)d_in[6];
  float* out = (float*)d_out;
  char* ws = (char*)d_ws;

  constexpr size_t SZ_MAT = (size_t)BQ * CHN * NP * 4;           // 9,633,792
  constexpr size_t SZ_STR = (size_t)BQ * NT * NFRAG * 512 * 2;   // 14,450,688
  constexpr size_t SZ_PL  = (size_t)BQ * NLIST * NP * KNN * 4;   // 14,450,688
  constexpr size_t OFF_H   = 0;
  constexpr size_t OFF_PD  = 0;
  constexpr size_t OFF_PI  = OFF_PD + SZ_PL;
  constexpr size_t OFF_A   = 0;
  constexpr size_t OFF_AST = 2 * SZ_PL;
  constexpr size_t OFF_U   = OFF_AST;            // ast dead after k4; 28.9 MB holds u
  constexpr size_t OFF_NRM = OFF_AST + 2 * SZ_STR;
  constexpr size_t OFF_OL  = OFF_NRM;
  constexpr size_t OFF_FE  = OFF_NRM + SZ_MAT;
  constexpr size_t OFF_SQ  = OFF_FE + SZ_MAT;
  constexpr size_t OFF_ST1 = OFF_SQ + (size_t)BQ * NP * 4;
  constexpr size_t OFF_ST2 = OFF_ST1 + (size_t)BQ * CHN * 2 * 4;
  constexpr size_t OFF_NI  = OFF_ST2 + (size_t)BQ * CHN * 2 * 4;

  float* h   = (float*)(ws + OFF_H);
  float* fe  = (float*)(ws + OFF_FE);
  float* nrm = (float*)(ws + OFF_NRM);
  float* sq  = (float*)(ws + OFF_SQ);
  float* st1 = (float*)(ws + OFF_ST1);
  float* st2 = (float*)(ws + OFF_ST2);
  int*   ni  = (int*)(ws + OFF_NI);
  ushort* ast = (ushort*)(ws + OFF_AST);
  float* pd  = (float*)(ws + OFF_PD);
  int*   pi  = (int*)(ws + OFF_PI);
  float* aA  = (float*)(ws + OFF_A);
  float* uU  = (float*)(ws + OFF_U);
  float* ol  = (float*)(ws + OFF_OL);

  k1_conv1<<<dim3(NP / 64, BQ), 256, 0, stream>>>(x, f1w, f1b, h);
  k2_stats<<<dim3(BQ * CHN), 256, 0, stream>>>(h, st1);
  k3_norm<<<dim3(NP / 32, BQ), 256, 0, stream>>>(h, st1, fe, nrm, sq);
  k3b_prep<<<dim3(NT, BQ), 256, 0, stream>>>(nrm, ast);
  k4_mfma<<<dim3((NT / 4) * MCH * BQ), 256, 0, stream>>>(ast, sq, pd, pi);
  k4b_merge<<<dim3(BQ * NP * 4 / 256), 256, 0, stream>>>(pd, pi, ni);
  k5_au<<<dim3(NP / 32, BQ), 256, 0, stream>>>(fe, gw, gb, aA, uU);
  k6_edge<<<dim3(NP / 32, BQ), 256, 0, stream>>>(aA, uU, ni, f2w, f2b, ol);
  k2_stats<<<dim3(BQ * CHN), 256, 0, stream>>>(ol, st2);
  k8_final<<<dim3(BQ * CHN * NP / 256), 256, 0, stream>>>(ol, st2, x, out);
}